// Round 1
// baseline (1833.450 us; speedup 1.0000x reference)
//
#include <hip/hip_runtime.h>
#include <math.h>

#define PI_F 3.14159265358979323846f

// ======================= SIFT descriptor =======================
// One block per patch. Patch is a stride-K subsample of the image:
// patch[i][j] = x[b, i*K+ki, j*K+kj], n = b*K*K + (ki*K+kj).
// Output desc stored at out[n*128 + d] which IS the (B,128,K,K) layout.
template<int PS, int K, int NT>
__global__ __launch_bounds__(NT)
void sift_kernel(const float* __restrict__ x, float* __restrict__ out)
{
    constexpr int NPIX = PS*PS;
    constexpr int BK = 2*(PS/5);       // 12 / 6 / 2
    constexpr int STRIDE = PS/4;       // 8 / 4 / 2
    constexpr int PAD = BK/4;          // 3 / 1 / 0
    constexpr float HALF = BK*0.5f;

    __shared__ float patch[NPIX];
    __shared__ float bins[8*NPIX];
    __shared__ float g1[PS];
    __shared__ float desc[128];
    __shared__ float red[NT];
    __shared__ float gsum_s;

    const int tid = threadIdx.x;
    const int n = blockIdx.x;
    const int b = n / (K*K);
    const int c = n % (K*K);
    const int ki = c / K;
    const int kj = c % K;

    const float* xb = x + (size_t)b*224*224;
    for (int idx = tid; idx < NPIX; idx += NT) {
        int i = idx / PS, j = idx - i*PS;
        patch[idx] = xb[(i*K + ki)*224 + (j*K + kj)];
    }
    if (tid < PS) {
        const float sigma = (float)PS * 0.70710678118654752440f;  // PS/sqrt(2)
        float xv = (float)tid - (PS-1)*0.5f;
        float t = xv / sigma;
        g1[tid] = expf(-0.5f*t*t);
    }
    for (int idx = tid; idx < 8*NPIX; idx += NT) bins[idx] = 0.f;
    __syncthreads();
    if (tid == 0) {
        float s = 0.f;
        for (int i = 0; i < PS; i++) s += g1[i];
        gsum_s = s;
    }
    __syncthreads();
    const float ginv = 1.0f / (gsum_s*gsum_s);

    for (int idx = tid; idx < NPIX; idx += NT) {
        int i = idx / PS, j = idx - i*PS;
        int jm = j > 0 ? j-1 : 0, jp = j < PS-1 ? j+1 : PS-1;
        int im = i > 0 ? i-1 : 0, ip = i < PS-1 ? i+1 : PS-1;
        float gx = 0.5f*(patch[i*PS+jp] - patch[i*PS+jm]);
        float gy = 0.5f*(patch[ip*PS+j] - patch[im*PS+j]);
        float mag = sqrtf(gx*gx + gy*gy + 1e-10f) * (g1[i]*g1[j]*ginv);
        float ori = atan2f(gy, gx + 1e-10f) + 2.f*PI_F;   // (pi, 3pi]
        float obig = ori * (8.f/(2.f*PI_F));               // (4, 12]
        float bo0f = floorf(obig);
        float w1 = obig - bo0f;
        int bo0 = ((int)bo0f) & 7;
        int bo1 = (bo0 + 1) & 7;
        bins[bo0*NPIX + idx] = (1.f - w1)*mag;
        bins[bo1*NPIX + idx] = w1*mag;
    }
    __syncthreads();

    // Triangular pooling: 8 orientations x 4x4 spatial windows
    for (int t = tid; t < 128; t += NT) {
        int o = t >> 4;
        int py = (t >> 2) & 3;
        int px = t & 3;
        int sy = py*STRIDE - PAD;
        int sx = px*STRIDE - PAD;
        const float* bo = bins + o*NPIX;
        float acc = 0.f;
        for (int di = 0; di < BK; di++) {
            int i = sy + di;
            if (i < 0 || i >= PS) continue;
            float wi = HALF - fabsf((float)di + 0.5f - HALF);
            for (int dj = 0; dj < BK; dj++) {
                int j = sx + dj;
                if (j < 0 || j >= PS) continue;
                float wj = HALF - fabsf((float)dj + 0.5f - HALF);
                acc += bo[i*PS + j] * (wi*wj);
            }
        }
        desc[t] = acc * (1.0f/(HALF*HALF));
    }
    __syncthreads();

    // normalize chain: L2 -> clip 0.2 -> L2 -> rootsift
    float d = (tid < 128) ? desc[tid] : 0.f;
    red[tid] = d*d; __syncthreads();
    for (int s = NT/2; s > 0; s >>= 1) { if (tid < s) red[tid] += red[tid+s]; __syncthreads(); }
    float nrm = sqrtf(red[0]); __syncthreads();
    d = d / fmaxf(nrm, 1e-12f);
    d = fminf(fmaxf(d, 0.f), 0.2f);
    red[tid] = d*d; __syncthreads();
    for (int s = NT/2; s > 0; s >>= 1) { if (tid < s) red[tid] += red[tid+s]; __syncthreads(); }
    nrm = sqrtf(red[0]); __syncthreads();
    d = d / fmaxf(nrm, 1e-12f);
    red[tid] = d; __syncthreads();   // d >= 0, so sum == sum(|d|)
    for (int s = NT/2; s > 0; s >>= 1) { if (tid < s) red[tid] += red[tid+s]; __syncthreads(); }
    float ssum = red[0];
    d = sqrtf(d / fmaxf(ssum, 1e-12f) + 1e-10f);
    if (tid < 128) out[(size_t)n*128 + tid] = d;
}

// ============ fused ConvTranspose2d(k4,s2,p1) + GroupNorm + ReLU ============
// One block per (batch, group). CG = COUT/G channels per group.
// Input = concat([in0 (CIN0 ch), in1 (CIN1 ch)]).
template<int CIN0, int CIN1, int COUT, int G, int HIN>
__global__ __launch_bounds__(256)
void convt_gn_relu(const float* __restrict__ in0, const float* __restrict__ in1,
                   const float* __restrict__ w, const float* __restrict__ bias,
                   const float* __restrict__ gw, const float* __restrict__ gb,
                   float* __restrict__ out)
{
    constexpr int CIN = CIN0 + CIN1;
    constexpr int CG = COUT / G;
    constexpr int H0 = HIN*2;
    constexpr int SP = H0*H0;
    constexpr int NOUT = CG*SP;
    constexpr int HIN2 = HIN*HIN;

    __shared__ float wl[CIN*CG*16];
    __shared__ float red[256];

    const int tid = threadIdx.x;
    const int b = blockIdx.x / G;
    const int g = blockIdx.x - b*G;

    for (int idx = tid; idx < CIN*CG*16; idx += 256) {
        int ci = idx / (CG*16);
        int r = idx - ci*(CG*16);
        int col = r >> 4;
        int t = r & 15;
        wl[idx] = w[(ci*COUT + g*CG + col)*16 + t];
    }
    __syncthreads();

    const float* i0 = in0 + (size_t)b*CIN0*HIN2;
    const float* i1 = (CIN1 > 0) ? (in1 + (size_t)b*CIN1*HIN2) : in0;
    float* ob = out + ((size_t)b*COUT + g*CG)*SP;

    float lsum = 0.f, lsq = 0.f;
    for (int t = tid; t < NOUT; t += 256) {
        int col = t / SP;
        int rem = t - col*SP;
        int oy = rem / H0, ox = rem - oy*H0;
        // valid taps: ky in {pA, pA+2} with iy = (oy+1-ky)/2
        int pA = (oy+1)&1;
        int iyA = (oy+1-pA)>>1;
        int iyB = iyA - 1;
        int qA = (ox+1)&1;
        int ixA = (ox+1-qA)>>1;
        int ixB = ixA - 1;
        const bool vyA = iyA < HIN;
        const bool vyB = iyB >= 0;
        const bool vxA = ixA < HIN;
        const bool vxB = ixB >= 0;
        float acc = bias[g*CG + col];
        for (int ci = 0; ci < CIN; ci++) {
            const float* ip;
            if (CIN1 == 0 || ci < CIN0) ip = i0 + ci*HIN2;
            else ip = i1 + (ci - CIN0)*HIN2;
            const float* wcc = wl + (ci*CG + col)*16;
            if (vyA) {
                const float* row = ip + iyA*HIN;
                if (vxA) acc += row[ixA]*wcc[pA*4+qA];
                if (vxB) acc += row[ixB]*wcc[pA*4+qA+2];
            }
            if (vyB) {
                const float* row = ip + iyB*HIN;
                if (vxA) acc += row[ixA]*wcc[(pA+2)*4+qA];
                if (vxB) acc += row[ixB]*wcc[(pA+2)*4+qA+2];
            }
        }
        ob[t] = acc;
        lsum += acc;
        lsq  += acc*acc;
    }
    red[tid] = lsum; __syncthreads();
    for (int s = 128; s > 0; s >>= 1){ if (tid < s) red[tid] += red[tid+s]; __syncthreads(); }
    float total = red[0]; __syncthreads();
    red[tid] = lsq; __syncthreads();
    for (int s = 128; s > 0; s >>= 1){ if (tid < s) red[tid] += red[tid+s]; __syncthreads(); }
    float totsq = red[0];
    float mean = total * (1.0f/NOUT);
    float var  = totsq * (1.0f/NOUT) - mean*mean;
    float inv  = rsqrtf(var + 1e-5f);
    for (int t = tid; t < NOUT; t += 256) {
        int col = t / SP;
        int cglob = g*CG + col;
        float v = ob[t];                       // re-read own writes (same thread)
        v = (v - mean)*inv*gw[cglob] + gb[cglob];
        ob[t] = fmaxf(v, 0.f);
    }
}

// ======================= 1x1 conv (skip connections) =======================
template<int CO, int S>
__global__ __launch_bounds__(256)
void conv1x1(const float* __restrict__ in, const float* __restrict__ w,
             const float* __restrict__ bias, float* __restrict__ out)
{
    int idx = blockIdx.x*256 + threadIdx.x;
    if (idx >= 16*CO*S) return;
    int s = idx % S; int r = idx / S; int co = r % CO; int b = r / CO;
    const float* ib = in + (size_t)b*128*S + s;
    const float* wr = w + co*128;
    float acc = bias[co];
    for (int c = 0; c < 128; c++) acc += wr[c]*ib[c*S];
    out[idx] = acc;
}

// ======================= final ConvTranspose2d (4->2) =======================
__global__ __launch_bounds__(256)
void convt_final(const float* __restrict__ in, const float* __restrict__ w,
                 const float* __restrict__ bias, float* __restrict__ out)
{
    __shared__ float wl[128];
    __shared__ float bl[2];
    int tid = threadIdx.x;
    if (tid < 128) wl[tid] = w[tid];
    if (tid < 2) bl[tid] = bias[tid];
    __syncthreads();
    int idx = blockIdx.x*256 + tid;          // 16*2*224*224 = 1605632 exactly
    int ox = idx % 224; int r = idx / 224;
    int oy = r % 224; r /= 224;
    int co = r % 2; int b = r / 2;
    int pA = (oy+1)&1, iyA = (oy+1-pA)>>1, iyB = iyA-1;
    int qA = (ox+1)&1, ixA = (ox+1-qA)>>1, ixB = ixA-1;
    const float* ib = in + (size_t)b*4*112*112;
    float acc = bl[co];
    for (int ci = 0; ci < 4; ci++){
        const float* ip = ib + ci*112*112;
        const float* wc = wl + (ci*2+co)*16;
        if (iyA < 112) {
            const float* row = ip + iyA*112;
            if (ixA < 112) acc += row[ixA]*wc[pA*4+qA];
            if (ixB >= 0)  acc += row[ixB]*wc[pA*4+qA+2];
        }
        if (iyB >= 0) {
            const float* row = ip + iyB*112;
            if (ixA < 112) acc += row[ixA]*wc[(pA+2)*4+qA];
            if (ixB >= 0)  acc += row[ixB]*wc[(pA+2)*4+qA+2];
        }
    }
    out[idx] = acc;
}

// ============== joint bilateral (5x5, l1 color on guide=x) + tanh*scale ==============
__global__ __launch_bounds__(256)
void bilateral_tanh(const float* __restrict__ x, const float* __restrict__ pre,
                    float* __restrict__ out)
{
    int idx = blockIdx.x*256 + threadIdx.x;    // 16*224*224 = 802816 exactly
    int px = idx % 224; int r = idx / 224;
    int py = r % 224; int b = r / 224;
    int s = py*224 + px;
    const float* xb = x + (size_t)b*50176;
    const float* p0 = pre + (size_t)b*2*50176;
    const float* p1 = p0 + 50176;
    float center = xb[s];
    float g[5];
    {
        float sm = 0.f;
        for (int i = 0; i < 5; i++){ float t = (i-2)/1.5f; g[i] = expf(-0.5f*t*t); sm += g[i]; }
        for (int i = 0; i < 5; i++) g[i] /= sm;
    }
    float wsum = 0.f, a0 = 0.f, a1 = 0.f;
    for (int di = -2; di <= 2; di++){
        int yy = py + di; yy = yy < 0 ? -yy : (yy > 223 ? 446 - yy : yy);
        for (int dj = -2; dj <= 2; dj++){
            int xx = px + dj; xx = xx < 0 ? -xx : (xx > 223 ? 446 - xx : xx);
            int o = yy*224 + xx;
            float dg = xb[o] - center;                 // guide has 2 identical ch -> l1 sum = 2|dg|
            float wgt = g[di+2]*g[dj+2]*__expf(-200.f*dg*dg);  // -0.5/0.01 * (2|dg|)^2
            wsum += wgt;
            a0 += wgt * p0[o];
            a1 += wgt * p1[o];
        }
    }
    float inv = 1.0f / wsum;
    out[(size_t)(b*2)*50176 + s]     = tanhf(a0*inv)*0.436f;
    out[(size_t)(b*2+1)*50176 + s]   = tanhf(a1*inv)*0.615f;
}

// ======================= launch =======================
extern "C" void kernel_launch(void* const* d_in, const int* in_sizes, int n_in,
                              void* d_out, int out_size, void* d_ws, size_t ws_size,
                              hipStream_t stream) {
    (void)in_sizes; (void)n_in; (void)out_size; (void)ws_size;
    const float* x   = (const float*)d_in[0];
    const float* d1w = (const float*)d_in[1];
    const float* d1b = (const float*)d_in[2];
    const float* g1w = (const float*)d_in[3];
    const float* g1b = (const float*)d_in[4];
    const float* s1w = (const float*)d_in[5];
    const float* s1b = (const float*)d_in[6];
    const float* d2w = (const float*)d_in[7];
    const float* d2b = (const float*)d_in[8];
    const float* g2w = (const float*)d_in[9];
    const float* g2b = (const float*)d_in[10];
    const float* s2w = (const float*)d_in[11];
    const float* s2b = (const float*)d_in[12];
    const float* d3w = (const float*)d_in[13];
    const float* d3b = (const float*)d_in[14];
    const float* g3w = (const float*)d_in[15];
    const float* g3b = (const float*)d_in[16];
    const float* d4w = (const float*)d_in[17];
    const float* d4b = (const float*)d_in[18];
    const float* g4w = (const float*)d_in[19];
    const float* g4b = (const float*)d_in[20];
    const float* fw  = (const float*)d_in[21];
    const float* fb  = (const float*)d_in[22];
    float* out = (float*)d_out;

    float* ws  = (float*)d_ws;
    float* s7  = ws;                  // 16*128*49      = 100352
    float* s14 = s7  + 100352;        // 16*128*196     = 401408
    float* s28 = s14 + 401408;        // 16*128*784     = 1605632
    float* h1  = s28 + 1605632;       // 16*32*196      = 100352
    float* sk1 = h1  + 100352;        // 16*32*196      = 100352
    float* h2  = sk1 + 100352;        // 16*16*784      = 200704
    float* sk2 = h2  + 200704;        // 16*16*784      = 200704
    float* h3  = sk2 + 200704;        // 16*8*3136      = 401408
    float* h4  = h3  + 401408;        // 16*4*12544     = 802816
    float* pre = h4  + 802816;        // 16*2*50176     = 1605632
    // total ~5.5M floats (~22 MB) of ws

    sift_kernel<32, 7, 256><<<784,   256, 0, stream>>>(x, s7);
    sift_kernel<16,14, 256><<<3136,  256, 0, stream>>>(x, s14);
    sift_kernel< 8,28, 128><<<12544, 128, 0, stream>>>(x, s28);

    convt_gn_relu<128, 0, 32, 8,  7><<<16*8, 256, 0, stream>>>(s7,  nullptr, d1w, d1b, g1w, g1b, h1);
    conv1x1<32, 196><<<392, 256, 0, stream>>>(s14, s1w, s1b, sk1);
    convt_gn_relu< 32,32, 16, 4, 14><<<16*4, 256, 0, stream>>>(h1,  sk1,     d2w, d2b, g2w, g2b, h2);
    conv1x1<16, 784><<<784, 256, 0, stream>>>(s28, s2w, s2b, sk2);
    convt_gn_relu< 16,16,  8, 2, 28><<<16*2, 256, 0, stream>>>(h2,  sk2,     d3w, d3b, g3w, g3b, h3);
    convt_gn_relu<  8, 0,  4, 1, 56><<<16,   256, 0, stream>>>(h3,  nullptr, d4w, d4b, g4w, g4b, h4);

    convt_final<<<6272, 256, 0, stream>>>(h4, fw, fb, pre);
    bilateral_tanh<<<3136, 256, 0, stream>>>(x, pre, out);
}

// Round 2
// 444.883 us; speedup vs baseline: 4.1212x; 4.1212x over previous
//
#include <hip/hip_runtime.h>
#include <math.h>

#define PI_F 3.14159265358979323846f

// ======================= SIFT descriptor =======================
// One block per patch. Patch is a stride-K subsample of the image:
// patch[i][j] = x[b, i*K+ki, j*K+kj], n = b*K*K + (ki*K+kj).
// Output desc stored at out[n*128 + d] which IS the (B,128,K,K) layout.
template<int PS, int K, int NT>
__global__ __launch_bounds__(NT)
void sift_kernel(const float* __restrict__ x, float* __restrict__ out)
{
    constexpr int NPIX = PS*PS;
    constexpr int BK = 2*(PS/5);       // 12 / 6 / 2
    constexpr int STRIDE = PS/4;       // 8 / 4 / 2
    constexpr int PAD = BK/4;          // 3 / 1 / 0
    constexpr float HALF = BK*0.5f;

    __shared__ float patch[NPIX];
    __shared__ float bins[8*NPIX];
    __shared__ float g1[PS];
    __shared__ float desc[128];
    __shared__ float red[NT];
    __shared__ float gsum_s;

    const int tid = threadIdx.x;
    const int n = blockIdx.x;
    const int b = n / (K*K);
    const int c = n % (K*K);
    const int ki = c / K;
    const int kj = c % K;

    const float* xb = x + (size_t)b*224*224;
    for (int idx = tid; idx < NPIX; idx += NT) {
        int i = idx / PS, j = idx - i*PS;
        patch[idx] = xb[(i*K + ki)*224 + (j*K + kj)];
    }
    if (tid < PS) {
        const float sigma = (float)PS * 0.70710678118654752440f;  // PS/sqrt(2)
        float xv = (float)tid - (PS-1)*0.5f;
        float t = xv / sigma;
        g1[tid] = expf(-0.5f*t*t);
    }
    for (int idx = tid; idx < 8*NPIX; idx += NT) bins[idx] = 0.f;
    __syncthreads();
    if (tid == 0) {
        float s = 0.f;
        for (int i = 0; i < PS; i++) s += g1[i];
        gsum_s = s;
    }
    __syncthreads();
    const float ginv = 1.0f / (gsum_s*gsum_s);

    for (int idx = tid; idx < NPIX; idx += NT) {
        int i = idx / PS, j = idx - i*PS;
        int jm = j > 0 ? j-1 : 0, jp = j < PS-1 ? j+1 : PS-1;
        int im = i > 0 ? i-1 : 0, ip = i < PS-1 ? i+1 : PS-1;
        float gx = 0.5f*(patch[i*PS+jp] - patch[i*PS+jm]);
        float gy = 0.5f*(patch[ip*PS+j] - patch[im*PS+j]);
        float mag = sqrtf(gx*gx + gy*gy + 1e-10f) * (g1[i]*g1[j]*ginv);
        float ori = atan2f(gy, gx + 1e-10f) + 2.f*PI_F;   // (pi, 3pi]
        float obig = ori * (8.f/(2.f*PI_F));               // (4, 12]
        float bo0f = floorf(obig);
        float w1 = obig - bo0f;
        int bo0 = ((int)bo0f) & 7;
        int bo1 = (bo0 + 1) & 7;
        bins[bo0*NPIX + idx] = (1.f - w1)*mag;
        bins[bo1*NPIX + idx] = w1*mag;
    }
    __syncthreads();

    // Triangular pooling: 8 orientations x 4x4 spatial windows
    for (int t = tid; t < 128; t += NT) {
        int o = t >> 4;
        int py = (t >> 2) & 3;
        int px = t & 3;
        int sy = py*STRIDE - PAD;
        int sx = px*STRIDE - PAD;
        const float* bo = bins + o*NPIX;
        float acc = 0.f;
        for (int di = 0; di < BK; di++) {
            int i = sy + di;
            if (i < 0 || i >= PS) continue;
            float wi = HALF - fabsf((float)di + 0.5f - HALF);
            for (int dj = 0; dj < BK; dj++) {
                int j = sx + dj;
                if (j < 0 || j >= PS) continue;
                float wj = HALF - fabsf((float)dj + 0.5f - HALF);
                acc += bo[i*PS + j] * (wi*wj);
            }
        }
        desc[t] = acc * (1.0f/(HALF*HALF));
    }
    __syncthreads();

    // normalize chain: L2 -> clip 0.2 -> L2 -> rootsift
    float d = (tid < 128) ? desc[tid] : 0.f;
    red[tid] = d*d; __syncthreads();
    for (int s = NT/2; s > 0; s >>= 1) { if (tid < s) red[tid] += red[tid+s]; __syncthreads(); }
    float nrm = sqrtf(red[0]); __syncthreads();
    d = d / fmaxf(nrm, 1e-12f);
    d = fminf(fmaxf(d, 0.f), 0.2f);
    red[tid] = d*d; __syncthreads();
    for (int s = NT/2; s > 0; s >>= 1) { if (tid < s) red[tid] += red[tid+s]; __syncthreads(); }
    nrm = sqrtf(red[0]); __syncthreads();
    d = d / fmaxf(nrm, 1e-12f);
    red[tid] = d; __syncthreads();   // d >= 0, so sum == sum(|d|)
    for (int s = NT/2; s > 0; s >>= 1) { if (tid < s) red[tid] += red[tid+s]; __syncthreads(); }
    float ssum = red[0];
    d = sqrtf(d / fmaxf(ssum, 1e-12f) + 1e-10f);
    if (tid < 128) out[(size_t)n*128 + tid] = d;
}

// =================== zero the GN stats buffer ===================
__global__ __launch_bounds__(256)
void zero_stats(float* __restrict__ stats, int n)
{
    int i = blockIdx.x*256 + threadIdx.x;
    if (i < n) stats[i] = 0.f;
}

// ============ ConvTranspose2d(k4,s2,p1) + partial GN stats ============
// Grid: (chunksPerGroup, B*G). One thread per output element of the group.
// stats[bg*2] += sum, stats[bg*2+1] += sumsq  (atomics, ~<=196 per address)
template<int CIN0, int CIN1, int COUT, int G, int HIN>
__global__ __launch_bounds__(256)
void convt_stats(const float* __restrict__ in0, const float* __restrict__ in1,
                 const float* __restrict__ w, const float* __restrict__ bias,
                 float* __restrict__ out, float* __restrict__ stats)
{
    constexpr int CIN = CIN0 + CIN1;
    constexpr int CG = COUT / G;
    constexpr int H0 = HIN*2;
    constexpr int SP = H0*H0;
    constexpr int NG = CG*SP;          // elements per (b,g) group
    constexpr int HIN2 = HIN*HIN;

    __shared__ float wl[CIN*CG*16];
    __shared__ float red[256];

    const int tid = threadIdx.x;
    const int bg = blockIdx.y;
    const int b = bg / G;
    const int g = bg - b*G;

    for (int idx = tid; idx < CIN*CG*16; idx += 256) {
        int ci = idx / (CG*16);
        int r = idx - ci*(CG*16);
        int col = r >> 4;
        int t = r & 15;
        wl[idx] = w[(ci*COUT + g*CG + col)*16 + t];
    }
    __syncthreads();

    const float* i0 = in0 + (size_t)b*CIN0*HIN2;
    const float* i1 = (CIN1 > 0) ? (in1 + (size_t)b*CIN1*HIN2) : in0;
    float* ob = out + ((size_t)b*COUT + g*CG)*SP;

    const int e = blockIdx.x*256 + tid;
    float acc = 0.f;
    if (e < NG) {
        int col = e / SP;
        int rem = e - col*SP;
        int oy = rem / H0, ox = rem - oy*H0;
        int pA = (oy+1)&1;
        int iyA = (oy+1-pA)>>1;
        int iyB = iyA - 1;
        int qA = (ox+1)&1;
        int ixA = (ox+1-qA)>>1;
        int ixB = ixA - 1;
        const bool vyA = iyA < HIN;
        const bool vyB = iyB >= 0;
        const bool vxA = ixA < HIN;
        const bool vxB = ixB >= 0;
        acc = bias[g*CG + col];
        for (int ci = 0; ci < CIN; ci++) {
            const float* ip;
            if (CIN1 == 0 || ci < CIN0) ip = i0 + ci*HIN2;
            else ip = i1 + (ci - CIN0)*HIN2;
            const float* wcc = wl + (ci*CG + col)*16;
            if (vyA) {
                const float* row = ip + iyA*HIN;
                if (vxA) acc += row[ixA]*wcc[pA*4+qA];
                if (vxB) acc += row[ixB]*wcc[pA*4+qA+2];
            }
            if (vyB) {
                const float* row = ip + iyB*HIN;
                if (vxA) acc += row[ixA]*wcc[(pA+2)*4+qA];
                if (vxB) acc += row[ixB]*wcc[(pA+2)*4+qA+2];
            }
        }
        ob[e] = acc;
    }
    float v = (e < NG) ? acc : 0.f;
    red[tid] = v; __syncthreads();
    for (int s = 128; s > 0; s >>= 1){ if (tid < s) red[tid] += red[tid+s]; __syncthreads(); }
    if (tid == 0) atomicAdd(&stats[bg*2], red[0]);
    __syncthreads();
    red[tid] = v*v; __syncthreads();
    for (int s = 128; s > 0; s >>= 1){ if (tid < s) red[tid] += red[tid+s]; __syncthreads(); }
    if (tid == 0) atomicAdd(&stats[bg*2+1], red[0]);
}

// ============ GroupNorm normalize + ReLU (elementwise) ============
template<int COUT, int G, int SP>
__global__ __launch_bounds__(256)
void gn_relu(float* __restrict__ buf, const float* __restrict__ stats,
             const float* __restrict__ gw, const float* __restrict__ gb)
{
    constexpr int CG = COUT / G;
    constexpr int NG = CG*SP;
    int idx = blockIdx.x*256 + threadIdx.x;
    if (idx >= 16*COUT*SP) return;
    int b = idx / (COUT*SP);
    int c = (idx / SP) % COUT;
    int g = c / CG;
    int bg = b*G + g;
    float sum = stats[bg*2], sq = stats[bg*2+1];
    float mean = sum * (1.0f/NG);
    float var  = sq * (1.0f/NG) - mean*mean;
    float inv  = rsqrtf(var + 1e-5f);
    float v = buf[idx];
    v = (v - mean)*inv*gw[c] + gb[c];
    buf[idx] = fmaxf(v, 0.f);
}

// ======================= 1x1 conv (skip connections) =======================
template<int CO, int S>
__global__ __launch_bounds__(256)
void conv1x1(const float* __restrict__ in, const float* __restrict__ w,
             const float* __restrict__ bias, float* __restrict__ out)
{
    int idx = blockIdx.x*256 + threadIdx.x;
    if (idx >= 16*CO*S) return;
    int s = idx % S; int r = idx / S; int co = r % CO; int b = r / CO;
    const float* ib = in + (size_t)b*128*S + s;
    const float* wr = w + co*128;
    float acc = bias[co];
    for (int c = 0; c < 128; c++) acc += wr[c]*ib[c*S];
    out[idx] = acc;
}

// ======================= final ConvTranspose2d (4->2) =======================
__global__ __launch_bounds__(256)
void convt_final(const float* __restrict__ in, const float* __restrict__ w,
                 const float* __restrict__ bias, float* __restrict__ out)
{
    __shared__ float wl[128];
    __shared__ float bl[2];
    int tid = threadIdx.x;
    if (tid < 128) wl[tid] = w[tid];
    if (tid < 2) bl[tid] = bias[tid];
    __syncthreads();
    int idx = blockIdx.x*256 + tid;          // 16*2*224*224 = 1605632 exactly
    int ox = idx % 224; int r = idx / 224;
    int oy = r % 224; r /= 224;
    int co = r % 2; int b = r / 2;
    int pA = (oy+1)&1, iyA = (oy+1-pA)>>1, iyB = iyA-1;
    int qA = (ox+1)&1, ixA = (ox+1-qA)>>1, ixB = ixA-1;
    const float* ib = in + (size_t)b*4*112*112;
    float acc = bl[co];
    for (int ci = 0; ci < 4; ci++){
        const float* ip = ib + ci*112*112;
        const float* wc = wl + (ci*2+co)*16;
        if (iyA < 112) {
            const float* row = ip + iyA*112;
            if (ixA < 112) acc += row[ixA]*wc[pA*4+qA];
            if (ixB >= 0)  acc += row[ixB]*wc[pA*4+qA+2];
        }
        if (iyB >= 0) {
            const float* row = ip + iyB*112;
            if (ixA < 112) acc += row[ixA]*wc[(pA+2)*4+qA];
            if (ixB >= 0)  acc += row[ixB]*wc[(pA+2)*4+qA+2];
        }
    }
    out[idx] = acc;
}

// ============== joint bilateral (5x5, l1 color on guide=x) + tanh*scale ==============
__global__ __launch_bounds__(256)
void bilateral_tanh(const float* __restrict__ x, const float* __restrict__ pre,
                    float* __restrict__ out)
{
    int idx = blockIdx.x*256 + threadIdx.x;    // 16*224*224 = 802816 exactly
    int px = idx % 224; int r = idx / 224;
    int py = r % 224; int b = r / 224;
    int s = py*224 + px;
    const float* xb = x + (size_t)b*50176;
    const float* p0 = pre + (size_t)b*2*50176;
    const float* p1 = p0 + 50176;
    float center = xb[s];
    float g[5];
    {
        float sm = 0.f;
        for (int i = 0; i < 5; i++){ float t = (i-2)/1.5f; g[i] = expf(-0.5f*t*t); sm += g[i]; }
        for (int i = 0; i < 5; i++) g[i] /= sm;
    }
    float wsum = 0.f, a0 = 0.f, a1 = 0.f;
    for (int di = -2; di <= 2; di++){
        int yy = py + di; yy = yy < 0 ? -yy : (yy > 223 ? 446 - yy : yy);
        for (int dj = -2; dj <= 2; dj++){
            int xx = px + dj; xx = xx < 0 ? -xx : (xx > 223 ? 446 - xx : xx);
            int o = yy*224 + xx;
            float dg = xb[o] - center;                 // guide has 2 identical ch -> l1 sum = 2|dg|
            float wgt = g[di+2]*g[dj+2]*__expf(-200.f*dg*dg);  // -0.5/0.01 * (2|dg|)^2
            wsum += wgt;
            a0 += wgt * p0[o];
            a1 += wgt * p1[o];
        }
    }
    float inv = 1.0f / wsum;
    out[(size_t)(b*2)*50176 + s]     = tanhf(a0*inv)*0.436f;
    out[(size_t)(b*2+1)*50176 + s]   = tanhf(a1*inv)*0.615f;
}

// ======================= launch =======================
extern "C" void kernel_launch(void* const* d_in, const int* in_sizes, int n_in,
                              void* d_out, int out_size, void* d_ws, size_t ws_size,
                              hipStream_t stream) {
    (void)in_sizes; (void)n_in; (void)out_size; (void)ws_size;
    const float* x   = (const float*)d_in[0];
    const float* d1w = (const float*)d_in[1];
    const float* d1b = (const float*)d_in[2];
    const float* g1w = (const float*)d_in[3];
    const float* g1b = (const float*)d_in[4];
    const float* s1w = (const float*)d_in[5];
    const float* s1b = (const float*)d_in[6];
    const float* d2w = (const float*)d_in[7];
    const float* d2b = (const float*)d_in[8];
    const float* g2w = (const float*)d_in[9];
    const float* g2b = (const float*)d_in[10];
    const float* s2w = (const float*)d_in[11];
    const float* s2b = (const float*)d_in[12];
    const float* d3w = (const float*)d_in[13];
    const float* d3b = (const float*)d_in[14];
    const float* g3w = (const float*)d_in[15];
    const float* g3b = (const float*)d_in[16];
    const float* d4w = (const float*)d_in[17];
    const float* d4b = (const float*)d_in[18];
    const float* g4w = (const float*)d_in[19];
    const float* g4b = (const float*)d_in[20];
    const float* fw  = (const float*)d_in[21];
    const float* fb  = (const float*)d_in[22];
    float* out = (float*)d_out;

    float* ws  = (float*)d_ws;
    float* s7  = ws;                  // 16*128*49      = 100352
    float* s14 = s7  + 100352;        // 16*128*196     = 401408
    float* s28 = s14 + 401408;        // 16*128*784     = 1605632
    float* h1  = s28 + 1605632;       // 16*32*196      = 100352
    float* sk1 = h1  + 100352;        // 16*32*196      = 100352
    float* h2  = sk1 + 100352;        // 16*16*784      = 200704
    float* sk2 = h2  + 200704;        // 16*16*784      = 200704
    float* h3  = sk2 + 200704;        // 16*8*3136      = 401408
    float* h4  = h3  + 401408;        // 16*4*12544     = 802816
    float* pre = h4  + 802816;        // 16*2*50176     = 1605632
    float* st1 = pre + 1605632;       // 16*8*2  = 256
    float* st2 = st1 + 256;           // 16*4*2  = 128
    float* st3 = st2 + 128;           // 16*2*2  = 64
    float* st4 = st3 + 64;            // 16*1*2  = 32
    // stats total 480 floats; ws total ~5.5M floats (~22 MB)

    // ---- SIFT features (independent of decoder) ----
    sift_kernel<32, 7, 256><<<784,   256, 0, stream>>>(x, s7);
    sift_kernel<16,14, 256><<<3136,  256, 0, stream>>>(x, s14);
    sift_kernel< 8,28, 128><<<12544, 128, 0, stream>>>(x, s28);

    // ---- zero GN stats (ws is re-poisoned before every call) ----
    zero_stats<<<2, 256, 0, stream>>>(st1, 480);

    // ---- skip connections ----
    conv1x1<32, 196><<<392, 256, 0, stream>>>(s14, s1w, s1b, sk1);
    conv1x1<16, 784><<<784, 256, 0, stream>>>(s28, s2w, s2b, sk2);

    // ---- layer 1: convT(128->32, 7->14), GN(8) ----  group elems = 4*196=784 -> 4 chunks
    convt_stats<128, 0, 32, 8,  7><<<dim3(4, 128),  256, 0, stream>>>(s7, nullptr, d1w, d1b, h1, st1);
    gn_relu<32, 8, 196><<<392, 256, 0, stream>>>(h1, st1, g1w, g1b);

    // ---- layer 2: convT(64->16, 14->28), GN(4) ---- group elems = 4*784=3136 -> 13 chunks
    convt_stats< 32,32, 16, 4, 14><<<dim3(13, 64),  256, 0, stream>>>(h1, sk1, d2w, d2b, h2, st2);
    gn_relu<16, 4, 784><<<784, 256, 0, stream>>>(h2, st2, g2w, g2b);

    // ---- layer 3: convT(32->8, 28->56), GN(2) ---- group elems = 4*3136=12544 -> 49 chunks
    convt_stats< 16,16,  8, 2, 28><<<dim3(49, 32),  256, 0, stream>>>(h2, sk2, d3w, d3b, h3, st3);
    gn_relu<8, 2, 3136><<<1568, 256, 0, stream>>>(h3, st3, g3w, g3b);

    // ---- layer 4: convT(8->4, 56->112), GN(1) ---- group elems = 4*12544=50176 -> 196 chunks
    convt_stats<  8, 0,  4, 1, 56><<<dim3(196, 16), 256, 0, stream>>>(h3, nullptr, d4w, d4b, h4, st4);
    gn_relu<4, 1, 12544><<<3136, 256, 0, stream>>>(h4, st4, g4w, g4b);

    // ---- head ----
    convt_final<<<6272, 256, 0, stream>>>(h4, fw, fb, pre);
    bilateral_tanh<<<3136, 256, 0, stream>>>(x, pre, out);
}

// Round 4
// 364.840 us; speedup vs baseline: 5.0254x; 1.2194x over previous
//
#include <hip/hip_runtime.h>
#include <math.h>

#define PI_F 3.14159265358979323846f

// ======================= SIFT descriptor =======================
template<int PS, int K, int NT>
__global__ __launch_bounds__(NT)
void sift_kernel(const float* __restrict__ x, float* __restrict__ out)
{
    constexpr int NPIX = PS*PS;
    constexpr int BK = 2*(PS/5);
    constexpr int STRIDE = PS/4;
    constexpr int PAD = BK/4;
    constexpr float HALF = BK*0.5f;

    __shared__ float patch[NPIX];
    __shared__ float bins[8*NPIX];
    __shared__ float g1[PS];
    __shared__ float desc[128];
    __shared__ float red[NT];
    __shared__ float gsum_s;

    const int tid = threadIdx.x;
    const int n = blockIdx.x;
    const int b = n / (K*K);
    const int c = n % (K*K);
    const int ki = c / K;
    const int kj = c % K;

    const float* xb = x + (size_t)b*224*224;
    for (int idx = tid; idx < NPIX; idx += NT) {
        int i = idx / PS, j = idx - i*PS;
        patch[idx] = xb[(i*K + ki)*224 + (j*K + kj)];
    }
    if (tid < PS) {
        const float sigma = (float)PS * 0.70710678118654752440f;
        float xv = (float)tid - (PS-1)*0.5f;
        float t = xv / sigma;
        g1[tid] = expf(-0.5f*t*t);
    }
    for (int idx = tid; idx < 8*NPIX; idx += NT) bins[idx] = 0.f;
    __syncthreads();
    if (tid == 0) {
        float s = 0.f;
        for (int i = 0; i < PS; i++) s += g1[i];
        gsum_s = s;
    }
    __syncthreads();
    const float ginv = 1.0f / (gsum_s*gsum_s);

    for (int idx = tid; idx < NPIX; idx += NT) {
        int i = idx / PS, j = idx - i*PS;
        int jm = j > 0 ? j-1 : 0, jp = j < PS-1 ? j+1 : PS-1;
        int im = i > 0 ? i-1 : 0, ip = i < PS-1 ? i+1 : PS-1;
        float gx = 0.5f*(patch[i*PS+jp] - patch[i*PS+jm]);
        float gy = 0.5f*(patch[ip*PS+j] - patch[im*PS+j]);
        float mag = sqrtf(gx*gx + gy*gy + 1e-10f) * (g1[i]*g1[j]*ginv);
        float ori = atan2f(gy, gx + 1e-10f) + 2.f*PI_F;
        float obig = ori * (8.f/(2.f*PI_F));
        float bo0f = floorf(obig);
        float w1 = obig - bo0f;
        int bo0 = ((int)bo0f) & 7;
        int bo1 = (bo0 + 1) & 7;
        bins[bo0*NPIX + idx] = (1.f - w1)*mag;
        bins[bo1*NPIX + idx] = w1*mag;
    }
    __syncthreads();

    for (int t = tid; t < 128; t += NT) {
        int o = t >> 4;
        int py = (t >> 2) & 3;
        int px = t & 3;
        int sy = py*STRIDE - PAD;
        int sx = px*STRIDE - PAD;
        const float* bo = bins + o*NPIX;
        float acc = 0.f;
        for (int di = 0; di < BK; di++) {
            int i = sy + di;
            if (i < 0 || i >= PS) continue;
            float wi = HALF - fabsf((float)di + 0.5f - HALF);
            for (int dj = 0; dj < BK; dj++) {
                int j = sx + dj;
                if (j < 0 || j >= PS) continue;
                float wj = HALF - fabsf((float)dj + 0.5f - HALF);
                acc += bo[i*PS + j] * (wi*wj);
            }
        }
        desc[t] = acc * (1.0f/(HALF*HALF));
    }
    __syncthreads();

    float d = (tid < 128) ? desc[tid] : 0.f;
    red[tid] = d*d; __syncthreads();
    for (int s = NT/2; s > 0; s >>= 1) { if (tid < s) red[tid] += red[tid+s]; __syncthreads(); }
    float nrm = sqrtf(red[0]); __syncthreads();
    d = d / fmaxf(nrm, 1e-12f);
    d = fminf(fmaxf(d, 0.f), 0.2f);
    red[tid] = d*d; __syncthreads();
    for (int s = NT/2; s > 0; s >>= 1) { if (tid < s) red[tid] += red[tid+s]; __syncthreads(); }
    nrm = sqrtf(red[0]); __syncthreads();
    d = d / fmaxf(nrm, 1e-12f);
    red[tid] = d; __syncthreads();
    for (int s = NT/2; s > 0; s >>= 1) { if (tid < s) red[tid] += red[tid+s]; __syncthreads(); }
    float ssum = red[0];
    d = sqrtf(d / fmaxf(ssum, 1e-12f) + 1e-10f);
    if (tid < 128) out[(size_t)n*128 + tid] = d;
}

// =================== zero the GN stats buffer ===================
__global__ __launch_bounds__(256)
void zero_stats(float* __restrict__ stats, int n)
{
    int i = blockIdx.x*256 + threadIdx.x;
    if (i < n) stats[i] = 0.f;
}

// ====== ConvTranspose2d(k4,s2,p1) [+GN-on-read of in0] + partial GN stats ======
// Thread = one spatial position x NCH output channels (group-aligned).
// Grid: (ceil(SP/256), B * COUT/NCH).
// Weights staged in LDS parity-permuted: wl2[pq][ci][j][tap], one float4 per (ci,j).
template<int CIN0, int CIN1, int COUT, int G, int HIN, int NCH, bool FUSE, int GIN, int NGIN>
__global__ __launch_bounds__(256)
void convt_fused(const float* __restrict__ in0, const float* __restrict__ in1,
                 const float* __restrict__ w, const float* __restrict__ bias,
                 const float* __restrict__ stats_in,
                 const float* __restrict__ gnw, const float* __restrict__ gnb,
                 float* __restrict__ out, float* __restrict__ stats_out)
{
    constexpr int CIN = CIN0 + CIN1;
    constexpr int CG = COUT / G;
    constexpr int NGRP = NCH / CG;      // groups covered by one thread
    constexpr int CB = COUT / NCH;      // channel-blocks
    constexpr int H0 = 2*HIN;
    constexpr int SP = H0*H0;
    constexpr int HIN2 = HIN*HIN;

    __shared__ float wl2[4*CIN*NCH*4];
    __shared__ float a_s[CIN0];
    __shared__ float b_s[CIN0];

    const int tid = threadIdx.x;
    const int by = blockIdx.y;
    const int b  = by / CB;
    const int cb = by - b*CB;
    const int c0 = cb*NCH;             // first output channel of this thread-block
    const int g0 = c0 / CG;            // first GN group

    // stage parity-permuted weights: wl2[((pq*CIN+ci)*NCH+j)*4+k]
    for (int idx = tid; idx < 4*CIN*NCH*4; idx += 256) {
        int k = idx & 3;
        int t = idx >> 2;
        int j = t % NCH; t /= NCH;
        int ci = t % CIN;
        int pq = t / CIN;
        int pA = pq >> 1, qA = pq & 1;
        int dy = pA + 2*(k>>1), dx = qA + 2*(k&1);
        wl2[idx] = w[(ci*COUT + c0 + j)*16 + dy*4 + dx];
    }
    if constexpr (FUSE) {
        for (int c = tid; c < CIN0; c += 256) {
            int gi = c / (CIN0/GIN);
            float s0 = stats_in[((size_t)b*GIN + gi)*2];
            float s1 = stats_in[((size_t)b*GIN + gi)*2 + 1];
            float mean = s0 * (1.f/NGIN);
            float var  = s1 * (1.f/NGIN) - mean*mean;
            float inv  = rsqrtf(var + 1e-5f);
            float a = inv * gnw[c];
            a_s[c] = a;
            b_s[c] = gnb[c] - mean*a;
        }
    }
    __syncthreads();

    const int e = blockIdx.x*256 + tid;
    const bool valid = e < SP;

    float acc[NCH];
    #pragma unroll
    for (int j = 0; j < NCH; j++) acc[j] = 0.f;

    if (valid) {
        int oy = e / H0, ox = e - oy*H0;
        int pA = (oy+1)&1, iyA = (oy+1-pA)>>1, iyB = iyA-1;
        int qA = (ox+1)&1, ixA = (ox+1-qA)>>1, ixB = ixA-1;
        float mYA = (iyA < HIN) ? 1.f : 0.f;
        float mYB = (iyB >= 0)  ? 1.f : 0.f;
        float mXA = (ixA < HIN) ? 1.f : 0.f;
        float mXB = (ixB >= 0)  ? 1.f : 0.f;
        float m0 = mYA*mXA, m1 = mYA*mXB, m2 = mYB*mXA, m3 = mYB*mXB;
        int iyAc = min(iyA, HIN-1), iyBc = max(iyB, 0);
        int ixAc = min(ixA, HIN-1), ixBc = max(ixB, 0);
        int oAA = iyAc*HIN + ixAc, oAB = iyAc*HIN + ixBc;
        int oBA = iyBc*HIN + ixAc, oBB = iyBc*HIN + ixBc;
        const float* wbase = wl2 + (pA*2+qA)*CIN*NCH*4;

        #pragma unroll
        for (int j = 0; j < NCH; j++) acc[j] = bias[c0 + j];

        const float* i0 = in0 + (size_t)b*CIN0*HIN2;
        #pragma unroll 4
        for (int ci = 0; ci < CIN0; ci++) {
            const float* ip = i0 + ci*HIN2;
            float l0 = ip[oAA], l1 = ip[oAB], l2 = ip[oBA], l3 = ip[oBB];
            if constexpr (FUSE) {
                float a = a_s[ci], bb = b_s[ci];
                l0 = fmaxf(l0*a + bb, 0.f);
                l1 = fmaxf(l1*a + bb, 0.f);
                l2 = fmaxf(l2*a + bb, 0.f);
                l3 = fmaxf(l3*a + bb, 0.f);
            }
            float t0 = l0*m0, t1 = l1*m1, t2 = l2*m2, t3 = l3*m3;
            const float* wr = wbase + ci*NCH*4;
            #pragma unroll
            for (int j = 0; j < NCH; j++) {
                const float4 wv = *(const float4*)(wr + j*4);
                acc[j] += t0*wv.x + t1*wv.y + t2*wv.z + t3*wv.w;
            }
        }
        if constexpr (CIN1 > 0) {
            const float* i1 = in1 + (size_t)b*CIN1*HIN2;
            #pragma unroll 4
            for (int ci = 0; ci < CIN1; ci++) {
                const float* ip = i1 + ci*HIN2;
                float t0 = ip[oAA]*m0, t1 = ip[oAB]*m1, t2 = ip[oBA]*m2, t3 = ip[oBB]*m3;
                const float* wr = wbase + (CIN0+ci)*NCH*4;
                #pragma unroll
                for (int j = 0; j < NCH; j++) {
                    const float4 wv = *(const float4*)(wr + j*4);
                    acc[j] += t0*wv.x + t1*wv.y + t2*wv.z + t3*wv.w;
                }
            }
        }
        float* ob = out + ((size_t)b*COUT + c0)*SP + e;
        #pragma unroll
        for (int j = 0; j < NCH; j++) ob[j*SP] = acc[j];
    }

    // per-(b,group) stats via wave reduce + atomics
    #pragma unroll
    for (int grp = 0; grp < NGRP; grp++) {
        float ps = 0.f, pq2 = 0.f;
        #pragma unroll
        for (int j = 0; j < CG; j++) {
            float v = acc[grp*CG + j];
            ps += v; pq2 += v*v;
        }
        #pragma unroll
        for (int off = 32; off > 0; off >>= 1) {
            ps  += __shfl_down(ps,  off);
            pq2 += __shfl_down(pq2, off);
        }
        if ((tid & 63) == 0) {
            atomicAdd(&stats_out[((size_t)b*G + g0 + grp)*2],     ps);
            atomicAdd(&stats_out[((size_t)b*G + g0 + grp)*2 + 1], pq2);
        }
    }
}

// ======================= 1x1 conv, 4 outputs/thread =======================
template<int CO, int S>
__global__ __launch_bounds__(256)
void conv1x1(const float* __restrict__ in, const float* __restrict__ w,
             const float* __restrict__ bias, float* __restrict__ out)
{
    __shared__ float wt[128*CO];   // transposed: wt[c*CO + co]
    const int tid = threadIdx.x;
    for (int i = tid; i < 128*CO; i += 256) {
        int c = i / CO, co = i - c*CO;
        wt[i] = w[co*128 + c];
    }
    __syncthreads();
    int idx = blockIdx.x*256 + tid;         // 16 * (CO/4) * S threads exactly
    int s = idx % S; int r = idx / S;
    int co4 = r % (CO/4); int b = r / (CO/4);
    int co = co4*4;
    const float* ib = in + (size_t)b*128*S + s;
    float acc0 = bias[co], acc1 = bias[co+1], acc2 = bias[co+2], acc3 = bias[co+3];
    #pragma unroll 8
    for (int c = 0; c < 128; c++) {
        float v = ib[c*S];
        const float4 wv = *(const float4*)&wt[c*CO + co];
        acc0 += v*wv.x; acc1 += v*wv.y; acc2 += v*wv.z; acc3 += v*wv.w;
    }
    float* ob = out + ((size_t)b*CO + co)*S + s;
    ob[0] = acc0; ob[S] = acc1; ob[2*S] = acc2; ob[3*S] = acc3;
}

// ======= final ConvTranspose2d (4->2) with GN-on-read of h4, 2 out/thread =======
__global__ __launch_bounds__(256)
void convt_final_fused(const float* __restrict__ in, const float* __restrict__ w,
                       const float* __restrict__ bias,
                       const float* __restrict__ stats_in,
                       const float* __restrict__ gnw, const float* __restrict__ gnb,
                       float* __restrict__ out)
{
    __shared__ float wl2[128];   // wl2[((pq*4+ci)*2+co)*4+k]
    __shared__ float a_s[4], b_s[4], bl[2];
    const int tid = threadIdx.x;
    const int b = blockIdx.y;
    if (tid < 128) {
        int k = tid & 3;
        int t = tid >> 2;
        int co = t & 1; t >>= 1;
        int ci = t & 3;
        int pq = t >> 2;
        int pA = pq >> 1, qA = pq & 1;
        int dy = pA + 2*(k>>1), dx = qA + 2*(k&1);
        wl2[tid] = w[(ci*2 + co)*16 + dy*4 + dx];
    }
    if (tid < 4) {
        float s0 = stats_in[(size_t)b*2];
        float s1 = stats_in[(size_t)b*2 + 1];
        float mean = s0 * (1.f/50176.f);
        float var  = s1 * (1.f/50176.f) - mean*mean;
        float inv  = rsqrtf(var + 1e-5f);
        float a = inv * gnw[tid];
        a_s[tid] = a;
        b_s[tid] = gnb[tid] - mean*a;
    }
    if (tid < 2) bl[tid] = bias[tid];
    __syncthreads();

    int e = blockIdx.x*256 + tid;           // < 50176 exactly (196 blocks)
    int oy = e / 224, ox = e - oy*224;
    int pA = (oy+1)&1, iyA = (oy+1-pA)>>1, iyB = iyA-1;
    int qA = (ox+1)&1, ixA = (ox+1-qA)>>1, ixB = ixA-1;
    float mYA = (iyA < 112) ? 1.f : 0.f;
    float mYB = (iyB >= 0)  ? 1.f : 0.f;
    float mXA = (ixA < 112) ? 1.f : 0.f;
    float mXB = (ixB >= 0)  ? 1.f : 0.f;
    float m0 = mYA*mXA, m1 = mYA*mXB, m2 = mYB*mXA, m3 = mYB*mXB;
    int iyAc = min(iyA, 111), iyBc = max(iyB, 0);
    int ixAc = min(ixA, 111), ixBc = max(ixB, 0);
    int oAA = iyAc*112 + ixAc, oAB = iyAc*112 + ixBc;
    int oBA = iyBc*112 + ixAc, oBB = iyBc*112 + ixBc;
    const float* wbase = wl2 + (pA*2+qA)*32;

    float acc0 = bl[0], acc1 = bl[1];
    const float* ib = in + (size_t)b*4*112*112;
    #pragma unroll
    for (int ci = 0; ci < 4; ci++) {
        const float* ip = ib + ci*112*112;
        float a = a_s[ci], bb = b_s[ci];
        float l0 = fmaxf(ip[oAA]*a + bb, 0.f);
        float l1 = fmaxf(ip[oAB]*a + bb, 0.f);
        float l2 = fmaxf(ip[oBA]*a + bb, 0.f);
        float l3 = fmaxf(ip[oBB]*a + bb, 0.f);
        float t0 = l0*m0, t1 = l1*m1, t2 = l2*m2, t3 = l3*m3;
        const float4 w0 = *(const float4*)(wbase + ci*8);
        const float4 w1 = *(const float4*)(wbase + ci*8 + 4);
        acc0 += t0*w0.x + t1*w0.y + t2*w0.z + t3*w0.w;
        acc1 += t0*w1.x + t1*w1.y + t2*w1.z + t3*w1.w;
    }
    float* ob = out + (size_t)b*2*50176 + e;
    ob[0] = acc0;
    ob[50176] = acc1;
}

// ============== joint bilateral (5x5, l1 color on guide=x) + tanh*scale ==============
__global__ __launch_bounds__(256)
void bilateral_tanh(const float* __restrict__ x, const float* __restrict__ pre,
                    float* __restrict__ out)
{
    // normalized 5-tap gaussian (sigma=1.5), precomputed
    const float g[5] = {0.1200783f, 0.2338817f, 0.2920800f, 0.2338817f, 0.1200783f};
    int idx = blockIdx.x*256 + threadIdx.x;    // 16*224*224 = 802816 exactly
    int px = idx % 224; int r = idx / 224;
    int py = r % 224; int b = r / 224;
    int s = py*224 + px;
    const float* xb = x + (size_t)b*50176;
    const float* p0 = pre + (size_t)b*2*50176;
    const float* p1 = p0 + 50176;
    float center = xb[s];
    float wsum = 0.f, a0 = 0.f, a1 = 0.f;
    #pragma unroll
    for (int di = -2; di <= 2; di++){
        int yy = py + di; yy = yy < 0 ? -yy : (yy > 223 ? 446 - yy : yy);
        #pragma unroll
        for (int dj = -2; dj <= 2; dj++){
            int xx = px + dj; xx = xx < 0 ? -xx : (xx > 223 ? 446 - xx : xx);
            int o = yy*224 + xx;
            float dg = xb[o] - center;
            float wgt = g[di+2]*g[dj+2]*__expf(-200.f*dg*dg);
            wsum += wgt;
            a0 += wgt * p0[o];
            a1 += wgt * p1[o];
        }
    }
    float inv = 1.0f / wsum;
    out[(size_t)(b*2)*50176 + s]     = tanhf(a0*inv)*0.436f;
    out[(size_t)(b*2+1)*50176 + s]   = tanhf(a1*inv)*0.615f;
}

// ======================= launch =======================
extern "C" void kernel_launch(void* const* d_in, const int* in_sizes, int n_in,
                              void* d_out, int out_size, void* d_ws, size_t ws_size,
                              hipStream_t stream) {
    (void)in_sizes; (void)n_in; (void)out_size; (void)ws_size;
    const float* x   = (const float*)d_in[0];
    const float* d1w = (const float*)d_in[1];
    const float* d1b = (const float*)d_in[2];
    const float* g1w = (const float*)d_in[3];
    const float* g1b = (const float*)d_in[4];
    const float* s1w = (const float*)d_in[5];
    const float* s1b = (const float*)d_in[6];
    const float* d2w = (const float*)d_in[7];
    const float* d2b = (const float*)d_in[8];
    const float* g2w = (const float*)d_in[9];
    const float* g2b = (const float*)d_in[10];
    const float* s2w = (const float*)d_in[11];
    const float* s2b = (const float*)d_in[12];
    const float* d3w = (const float*)d_in[13];
    const float* d3b = (const float*)d_in[14];
    const float* g3w = (const float*)d_in[15];
    const float* g3b = (const float*)d_in[16];
    const float* d4w = (const float*)d_in[17];
    const float* d4b = (const float*)d_in[18];
    const float* g4w = (const float*)d_in[19];
    const float* g4b = (const float*)d_in[20];
    const float* fw  = (const float*)d_in[21];
    const float* fb  = (const float*)d_in[22];
    float* out = (float*)d_out;

    float* ws  = (float*)d_ws;
    float* s7  = ws;                  // 16*128*49      = 100352
    float* s14 = s7  + 100352;        // 16*128*196     = 401408
    float* s28 = s14 + 401408;        // 16*128*784     = 1605632
    float* h1  = s28 + 1605632;       // 16*32*196      = 100352   (raw conv out)
    float* sk1 = h1  + 100352;        // 16*32*196      = 100352
    float* h2  = sk1 + 100352;        // 16*16*784      = 200704   (raw conv out)
    float* sk2 = h2  + 200704;        // 16*16*784      = 200704
    float* h3  = sk2 + 200704;        // 16*8*3136      = 401408   (raw conv out)
    float* h4  = h3  + 401408;        // 16*4*12544     = 802816   (raw conv out)
    float* pre = h4  + 802816;        // 16*2*50176     = 1605632
    float* st1 = pre + 1605632;       // 16*8*2  = 256
    float* st2 = st1 + 256;           // 16*4*2  = 128
    float* st3 = st2 + 128;           // 16*2*2  = 64
    float* st4 = st3 + 64;            // 16*1*2  = 32

    // ---- SIFT features ----
    sift_kernel<32, 7, 256><<<784,   256, 0, stream>>>(x, s7);
    sift_kernel<16,14, 256><<<3136,  256, 0, stream>>>(x, s14);
    sift_kernel< 8,28, 128><<<12544, 128, 0, stream>>>(x, s28);

    zero_stats<<<2, 256, 0, stream>>>(st1, 480);

    // ---- skip connections ----
    // threads = 16 * (CO/4) * S: CO=32,S=196 -> 25088 -> 98 blocks  (BUG in r2: was 49)
    conv1x1<32, 196><<<98,  256, 0, stream>>>(s14, s1w, s1b, sk1);
    // CO=16,S=784 -> 50176 -> 196 blocks
    conv1x1<16, 784><<<196, 256, 0, stream>>>(s28, s2w, s2b, sk2);

    // L1: convT(128->32, 7->14), GN(8). NCH=8 -> 4 channel-blocks. SP=196 -> 1 chunk.
    convt_fused<128, 0, 32, 8,  7, 8, false, 1, 1>
        <<<dim3(1, 16*4), 256, 0, stream>>>(s7, nullptr, d1w, d1b, nullptr, nullptr, nullptr, h1, st1);
    // L2: convT(64->16, 14->28), GN(4). in0=h1 via GN(8, NG=784). NCH=8 -> 2 cb. SP=784 -> 4 chunks.
    convt_fused< 32,32, 16, 4, 14, 8, true, 8, 784>
        <<<dim3(4, 16*2), 256, 0, stream>>>(h1, sk1, d2w, d2b, st1, g1w, g1b, h2, st2);
    // L3: convT(32->8, 28->56), GN(2). in0=h2 via GN(4, NG=3136). NCH=8 -> 1 cb. SP=3136 -> 13 chunks.
    convt_fused< 16,16,  8, 2, 28, 8, true, 4, 3136>
        <<<dim3(13, 16), 256, 0, stream>>>(h2, sk2, d3w, d3b, st2, g2w, g2b, h3, st3);
    // L4: convT(8->4, 56->112), GN(1). in0=h3 via GN(2, NG=12544). NCH=4 -> 1 cb. SP=12544 -> 49 chunks.
    convt_fused<  8, 0,  4, 1, 56, 4, true, 2, 12544>
        <<<dim3(49, 16), 256, 0, stream>>>(h3, nullptr, d4w, d4b, st3, g3w, g3b, h4, st4);

    // head: final convT reads h4 via GN(1, NG=50176)
    convt_final_fused<<<dim3(196, 16), 256, 0, stream>>>(h4, fw, fb, st4, g4w, g4b, pre);
    bilateral_tanh<<<3136, 256, 0, stream>>>(x, pre, out);
}

// Round 5
// 361.498 us; speedup vs baseline: 5.0718x; 1.0092x over previous
//
#include <hip/hip_runtime.h>
#include <math.h>

#define PI_F 3.14159265358979323846f

// ======================= SIFT descriptor =======================
template<int PS, int K, int NT>
__global__ __launch_bounds__(NT)
void sift_kernel(const float* __restrict__ x, float* __restrict__ out)
{
    constexpr int NPIX = PS*PS;
    constexpr int BK = 2*(PS/5);
    constexpr int STRIDE = PS/4;
    constexpr int PAD = BK/4;
    constexpr float HALF = BK*0.5f;

    __shared__ float patch[NPIX];
    __shared__ float bins[8*NPIX];
    __shared__ float g1[PS];
    __shared__ float desc[128];
    __shared__ float red[NT];
    __shared__ float gsum_s;

    const int tid = threadIdx.x;
    const int n = blockIdx.x;
    const int b = n / (K*K);
    const int c = n % (K*K);
    const int ki = c / K;
    const int kj = c % K;

    const float* xb = x + (size_t)b*224*224;
    for (int idx = tid; idx < NPIX; idx += NT) {
        int i = idx / PS, j = idx - i*PS;
        patch[idx] = xb[(i*K + ki)*224 + (j*K + kj)];
    }
    if (tid < PS) {
        const float sigma = (float)PS * 0.70710678118654752440f;
        float xv = (float)tid - (PS-1)*0.5f;
        float t = xv / sigma;
        g1[tid] = expf(-0.5f*t*t);
    }
    for (int idx = tid; idx < 8*NPIX; idx += NT) bins[idx] = 0.f;
    __syncthreads();
    if (tid == 0) {
        float s = 0.f;
        for (int i = 0; i < PS; i++) s += g1[i];
        gsum_s = s;
    }
    __syncthreads();
    const float ginv = 1.0f / (gsum_s*gsum_s);

    for (int idx = tid; idx < NPIX; idx += NT) {
        int i = idx / PS, j = idx - i*PS;
        int jm = j > 0 ? j-1 : 0, jp = j < PS-1 ? j+1 : PS-1;
        int im = i > 0 ? i-1 : 0, ip = i < PS-1 ? i+1 : PS-1;
        float gx = 0.5f*(patch[i*PS+jp] - patch[i*PS+jm]);
        float gy = 0.5f*(patch[ip*PS+j] - patch[im*PS+j]);
        float mag = sqrtf(gx*gx + gy*gy + 1e-10f) * (g1[i]*g1[j]*ginv);
        float ori = atan2f(gy, gx + 1e-10f) + 2.f*PI_F;
        float obig = ori * (8.f/(2.f*PI_F));
        float bo0f = floorf(obig);
        float w1 = obig - bo0f;
        int bo0 = ((int)bo0f) & 7;
        int bo1 = (bo0 + 1) & 7;
        bins[bo0*NPIX + idx] = (1.f - w1)*mag;
        bins[bo1*NPIX + idx] = w1*mag;
    }
    __syncthreads();

    for (int t = tid; t < 128; t += NT) {
        int o = t >> 4;
        int py = (t >> 2) & 3;
        int px = t & 3;
        int sy = py*STRIDE - PAD;
        int sx = px*STRIDE - PAD;
        const float* bo = bins + o*NPIX;
        float acc = 0.f;
        for (int di = 0; di < BK; di++) {
            int i = sy + di;
            if (i < 0 || i >= PS) continue;
            float wi = HALF - fabsf((float)di + 0.5f - HALF);
            for (int dj = 0; dj < BK; dj++) {
                int j = sx + dj;
                if (j < 0 || j >= PS) continue;
                float wj = HALF - fabsf((float)dj + 0.5f - HALF);
                acc += bo[i*PS + j] * (wi*wj);
            }
        }
        desc[t] = acc * (1.0f/(HALF*HALF));
    }
    __syncthreads();

    float d = (tid < 128) ? desc[tid] : 0.f;
    red[tid] = d*d; __syncthreads();
    for (int s = NT/2; s > 0; s >>= 1) { if (tid < s) red[tid] += red[tid+s]; __syncthreads(); }
    float nrm = sqrtf(red[0]); __syncthreads();
    d = d / fmaxf(nrm, 1e-12f);
    d = fminf(fmaxf(d, 0.f), 0.2f);
    red[tid] = d*d; __syncthreads();
    for (int s = NT/2; s > 0; s >>= 1) { if (tid < s) red[tid] += red[tid+s]; __syncthreads(); }
    nrm = sqrtf(red[0]); __syncthreads();
    d = d / fmaxf(nrm, 1e-12f);
    red[tid] = d; __syncthreads();
    for (int s = NT/2; s > 0; s >>= 1) { if (tid < s) red[tid] += red[tid+s]; __syncthreads(); }
    float ssum = red[0];
    d = sqrtf(d / fmaxf(ssum, 1e-12f) + 1e-10f);
    if (tid < 128) out[(size_t)n*128 + tid] = d;
}

// =================== zero the GN stats buffer ===================
__global__ __launch_bounds__(256)
void zero_stats(float* __restrict__ stats, int n)
{
    int i = blockIdx.x*256 + threadIdx.x;
    if (i < n) stats[i] = 0.f;
}

// ====== ConvTranspose2d(k4,s2,p1) via LDS input tile [+GN-on-read] + GN stats ======
// Block = (b, channel-block cb, row-tile rt). Covers RT output rows x full width H0,
// NCH output channels. Input window (zero-padded borders) staged in LDS; taps read
// from LDS -> no latency-exposed scattered global loads.
template<int CIN0, int CIN1, int COUT, int G, int HIN, int NCH, int RT, int NT,
         bool FUSE, int GIN, int NGIN>
__global__ __launch_bounds__(NT)
void convt_tiled(const float* __restrict__ in0, const float* __restrict__ in1,
                 const float* __restrict__ w, const float* __restrict__ bias,
                 const float* __restrict__ stats_in,
                 const float* __restrict__ gnw, const float* __restrict__ gnb,
                 float* __restrict__ out, float* __restrict__ stats_out)
{
    constexpr int CIN = CIN0 + CIN1;
    constexpr int CG = COUT / G;
    constexpr int NGRP = NCH / CG;
    constexpr int CB = COUT / NCH;
    constexpr int H0 = 2*HIN;
    constexpr int SP = H0*H0;
    constexpr int HIN2 = HIN*HIN;
    constexpr int NR = RT/2 + 2;       // input rows staged (incl. zero borders)
    constexpr int WIN = HIN + 2;       // input cols staged (zero col at each end)
    constexpr int TILE = CIN*NR*WIN;
    constexpr int WSTRIDE = CIN*NCH*4 + 4;   // +4 pad: kill parity-stride bank alias
    constexpr int NPOS = RT*H0;

    __shared__ float tile[TILE];
    __shared__ float wl2[4*WSTRIDE];
    __shared__ float a_s[CIN0];
    __shared__ float b_s[CIN0];

    const int tid = threadIdx.x;
    const int by = blockIdx.y;
    const int b  = by / CB;
    const int cb = by - b*CB;
    const int c0 = cb*NCH;
    const int g0 = c0 / CG;
    const int r0 = blockIdx.x * RT;    // first output row
    const int row0 = r0/2 - 1;         // first staged input row (may be -1)

    if constexpr (FUSE) {
        if (tid < CIN0) {
            int gi = tid / (CIN0/GIN);
            float s0 = stats_in[((size_t)b*GIN + gi)*2];
            float s1 = stats_in[((size_t)b*GIN + gi)*2 + 1];
            float mean = s0 * (1.f/NGIN);
            float var  = s1 * (1.f/NGIN) - mean*mean;
            float inv  = rsqrtf(var + 1e-5f);
            float a = inv * gnw[tid];
            a_s[tid] = a;
            b_s[tid] = gnb[tid] - mean*a;
        }
        __syncthreads();
    }

    // stage parity-permuted weights
    for (int idx = tid; idx < 4*CIN*NCH*4; idx += NT) {
        int k = idx & 3;
        int t2 = idx >> 2;
        int j = t2 % NCH; t2 /= NCH;
        int ci = t2 % CIN;
        int pq = t2 / CIN;
        int pA = pq >> 1, qA = pq & 1;
        int dy = pA + 2*(k>>1), dx = qA + 2*(k&1);
        wl2[pq*WSTRIDE + (ci*NCH + j)*4 + k] = w[(ci*COUT + c0 + j)*16 + dy*4 + dx];
    }

    // stage zero-padded input tile (GN+ReLU applied to in0 channels if FUSE)
    const float* i0 = in0 + (size_t)b*CIN0*HIN2;
    for (int idx = tid; idx < TILE; idx += NT) {
        int c = idx % WIN;
        int t2 = idx / WIN;
        int r = t2 % NR;
        int ci = t2 / NR;
        int iy = row0 + r, ix = c - 1;
        float v = 0.f;
        if (iy >= 0 && iy < HIN && ix >= 0 && ix < HIN) {
            if (CIN1 == 0 || ci < CIN0) {
                v = i0[ci*HIN2 + iy*HIN + ix];
                if constexpr (FUSE) v = fmaxf(v*a_s[ci] + b_s[ci], 0.f);
            } else {
                v = in1[((size_t)b*CIN1 + (ci-CIN0))*HIN2 + iy*HIN + ix];
            }
        }
        tile[idx] = v;
    }
    __syncthreads();

    float acc[NCH];
    #pragma unroll
    for (int j = 0; j < NCH; j++) acc[j] = 0.f;

    const bool active = tid < NPOS;
    if (active) {
        int oy = r0 + tid / H0, ox = tid % H0;
        int pA = (oy+1)&1, qA = (ox+1)&1;
        int iyA = (oy+1-pA)>>1, ixA = (ox+1-qA)>>1;
        int rA = iyA - row0;            // >= 1
        int cA = ixA + 1;               // >= 1
        int toff = rA*WIN + cA;
        const float* wbase = wl2 + (pA*2+qA)*WSTRIDE;

        #pragma unroll
        for (int j = 0; j < NCH; j++) acc[j] = bias[c0 + j];

        #pragma unroll 4
        for (int ci = 0; ci < CIN; ci++) {
            const float* tp = tile + ci*(NR*WIN) + toff;
            float l0 = tp[0];           // [iyA][ixA]
            float l1 = tp[-1];          // [iyA][ixB]
            float l2 = tp[-WIN];        // [iyB][ixA]
            float l3 = tp[-WIN-1];      // [iyB][ixB]
            const float* wr = wbase + ci*NCH*4;
            #pragma unroll
            for (int j = 0; j < NCH; j++) {
                const float4 wv = *(const float4*)(wr + j*4);
                acc[j] += l0*wv.x + l1*wv.y + l2*wv.z + l3*wv.w;
            }
        }
        float* ob = out + ((size_t)b*COUT + c0)*SP + r0*H0 + tid;
        #pragma unroll
        for (int j = 0; j < NCH; j++) ob[j*SP] = acc[j];
    }

    // per-(b,group) stats via wave reduce + atomics (inactive lanes contribute 0)
    #pragma unroll
    for (int grp = 0; grp < NGRP; grp++) {
        float ps = 0.f, pq2 = 0.f;
        #pragma unroll
        for (int j = 0; j < CG; j++) {
            float v = active ? acc[grp*CG + j] : 0.f;
            ps += v; pq2 += v*v;
        }
        #pragma unroll
        for (int off = 32; off > 0; off >>= 1) {
            ps  += __shfl_down(ps,  off);
            pq2 += __shfl_down(pq2, off);
        }
        if ((tid & 63) == 0) {
            atomicAdd(&stats_out[((size_t)b*G + g0 + grp)*2],     ps);
            atomicAdd(&stats_out[((size_t)b*G + g0 + grp)*2 + 1], pq2);
        }
    }
}

// ======================= 1x1 conv, 4 outputs/thread =======================
template<int CO, int S>
__global__ __launch_bounds__(256)
void conv1x1(const float* __restrict__ in, const float* __restrict__ w,
             const float* __restrict__ bias, float* __restrict__ out)
{
    __shared__ float wt[128*CO];   // transposed: wt[c*CO + co]
    const int tid = threadIdx.x;
    for (int i = tid; i < 128*CO; i += 256) {
        int c = i / CO, co = i - c*CO;
        wt[i] = w[co*128 + c];
    }
    __syncthreads();
    int idx = blockIdx.x*256 + tid;         // 16 * (CO/4) * S threads exactly
    int s = idx % S; int r = idx / S;
    int co4 = r % (CO/4); int b = r / (CO/4);
    int co = co4*4;
    const float* ib = in + (size_t)b*128*S + s;
    float acc0 = bias[co], acc1 = bias[co+1], acc2 = bias[co+2], acc3 = bias[co+3];
    #pragma unroll 8
    for (int c = 0; c < 128; c++) {
        float v = ib[c*S];
        const float4 wv = *(const float4*)&wt[c*CO + co];
        acc0 += v*wv.x; acc1 += v*wv.y; acc2 += v*wv.z; acc3 += v*wv.w;
    }
    float* ob = out + ((size_t)b*CO + co)*S + s;
    ob[0] = acc0; ob[S] = acc1; ob[2*S] = acc2; ob[3*S] = acc3;
}

// ======= final ConvTranspose2d (4->2) with GN-on-read of h4, 2 out/thread =======
__global__ __launch_bounds__(256)
void convt_final_fused(const float* __restrict__ in, const float* __restrict__ w,
                       const float* __restrict__ bias,
                       const float* __restrict__ stats_in,
                       const float* __restrict__ gnw, const float* __restrict__ gnb,
                       float* __restrict__ out)
{
    __shared__ float wl2[128];   // wl2[((pq*4+ci)*2+co)*4+k]
    __shared__ float a_s[4], b_s[4], bl[2];
    const int tid = threadIdx.x;
    const int b = blockIdx.y;
    if (tid < 128) {
        int k = tid & 3;
        int t = tid >> 2;
        int co = t & 1; t >>= 1;
        int ci = t & 3;
        int pq = t >> 2;
        int pA = pq >> 1, qA = pq & 1;
        int dy = pA + 2*(k>>1), dx = qA + 2*(k&1);
        wl2[tid] = w[(ci*2 + co)*16 + dy*4 + dx];
    }
    if (tid < 4) {
        float s0 = stats_in[(size_t)b*2];
        float s1 = stats_in[(size_t)b*2 + 1];
        float mean = s0 * (1.f/50176.f);
        float var  = s1 * (1.f/50176.f) - mean*mean;
        float inv  = rsqrtf(var + 1e-5f);
        float a = inv * gnw[tid];
        a_s[tid] = a;
        b_s[tid] = gnb[tid] - mean*a;
    }
    if (tid < 2) bl[tid] = bias[tid];
    __syncthreads();

    int e = blockIdx.x*256 + tid;           // < 50176 exactly (196 blocks)
    int oy = e / 224, ox = e - oy*224;
    int pA = (oy+1)&1, iyA = (oy+1-pA)>>1, iyB = iyA-1;
    int qA = (ox+1)&1, ixA = (ox+1-qA)>>1, ixB = ixA-1;
    float mYA = (iyA < 112) ? 1.f : 0.f;
    float mYB = (iyB >= 0)  ? 1.f : 0.f;
    float mXA = (ixA < 112) ? 1.f : 0.f;
    float mXB = (ixB >= 0)  ? 1.f : 0.f;
    float m0 = mYA*mXA, m1 = mYA*mXB, m2 = mYB*mXA, m3 = mYB*mXB;
    int iyAc = min(iyA, 111), iyBc = max(iyB, 0);
    int ixAc = min(ixA, 111), ixBc = max(ixB, 0);
    int oAA = iyAc*112 + ixAc, oAB = iyAc*112 + ixBc;
    int oBA = iyBc*112 + ixAc, oBB = iyBc*112 + ixBc;
    const float* wbase = wl2 + (pA*2+qA)*32;

    float acc0 = bl[0], acc1 = bl[1];
    const float* ib = in + (size_t)b*4*112*112;
    #pragma unroll
    for (int ci = 0; ci < 4; ci++) {
        const float* ip = ib + ci*112*112;
        float a = a_s[ci], bb = b_s[ci];
        float l0 = fmaxf(ip[oAA]*a + bb, 0.f);
        float l1 = fmaxf(ip[oAB]*a + bb, 0.f);
        float l2 = fmaxf(ip[oBA]*a + bb, 0.f);
        float l3 = fmaxf(ip[oBB]*a + bb, 0.f);
        float t0 = l0*m0, t1 = l1*m1, t2 = l2*m2, t3 = l3*m3;
        const float4 w0 = *(const float4*)(wbase + ci*8);
        const float4 w1 = *(const float4*)(wbase + ci*8 + 4);
        acc0 += t0*w0.x + t1*w0.y + t2*w0.z + t3*w0.w;
        acc1 += t0*w1.x + t1*w1.y + t2*w1.z + t3*w1.w;
    }
    float* ob = out + (size_t)b*2*50176 + e;
    ob[0] = acc0;
    ob[50176] = acc1;
}

// ============== joint bilateral (5x5, l1 color on guide=x) + tanh*scale ==============
__global__ __launch_bounds__(256)
void bilateral_tanh(const float* __restrict__ x, const float* __restrict__ pre,
                    float* __restrict__ out)
{
    const float g[5] = {0.1200783f, 0.2338817f, 0.2920800f, 0.2338817f, 0.1200783f};
    int idx = blockIdx.x*256 + threadIdx.x;    // 16*224*224 = 802816 exactly
    int px = idx % 224; int r = idx / 224;
    int py = r % 224; int b = r / 224;
    int s = py*224 + px;
    const float* xb = x + (size_t)b*50176;
    const float* p0 = pre + (size_t)b*2*50176;
    const float* p1 = p0 + 50176;
    float center = xb[s];
    float wsum = 0.f, a0 = 0.f, a1 = 0.f;
    #pragma unroll
    for (int di = -2; di <= 2; di++){
        int yy = py + di; yy = yy < 0 ? -yy : (yy > 223 ? 446 - yy : yy);
        #pragma unroll
        for (int dj = -2; dj <= 2; dj++){
            int xx = px + dj; xx = xx < 0 ? -xx : (xx > 223 ? 446 - xx : xx);
            int o = yy*224 + xx;
            float dg = xb[o] - center;
            float wgt = g[di+2]*g[dj+2]*__expf(-200.f*dg*dg);
            wsum += wgt;
            a0 += wgt * p0[o];
            a1 += wgt * p1[o];
        }
    }
    float inv = 1.0f / wsum;
    out[(size_t)(b*2)*50176 + s]     = tanhf(a0*inv)*0.436f;
    out[(size_t)(b*2+1)*50176 + s]   = tanhf(a1*inv)*0.615f;
}

// ======================= launch =======================
extern "C" void kernel_launch(void* const* d_in, const int* in_sizes, int n_in,
                              void* d_out, int out_size, void* d_ws, size_t ws_size,
                              hipStream_t stream) {
    (void)in_sizes; (void)n_in; (void)out_size; (void)ws_size;
    const float* x   = (const float*)d_in[0];
    const float* d1w = (const float*)d_in[1];
    const float* d1b = (const float*)d_in[2];
    const float* g1w = (const float*)d_in[3];
    const float* g1b = (const float*)d_in[4];
    const float* s1w = (const float*)d_in[5];
    const float* s1b = (const float*)d_in[6];
    const float* d2w = (const float*)d_in[7];
    const float* d2b = (const float*)d_in[8];
    const float* g2w = (const float*)d_in[9];
    const float* g2b = (const float*)d_in[10];
    const float* s2w = (const float*)d_in[11];
    const float* s2b = (const float*)d_in[12];
    const float* d3w = (const float*)d_in[13];
    const float* d3b = (const float*)d_in[14];
    const float* g3w = (const float*)d_in[15];
    const float* g3b = (const float*)d_in[16];
    const float* d4w = (const float*)d_in[17];
    const float* d4b = (const float*)d_in[18];
    const float* g4w = (const float*)d_in[19];
    const float* g4b = (const float*)d_in[20];
    const float* fw  = (const float*)d_in[21];
    const float* fb  = (const float*)d_in[22];
    float* out = (float*)d_out;

    float* ws  = (float*)d_ws;
    float* s7  = ws;                  // 16*128*49      = 100352
    float* s14 = s7  + 100352;        // 16*128*196     = 401408
    float* s28 = s14 + 401408;        // 16*128*784     = 1605632
    float* h1  = s28 + 1605632;       // 16*32*196      = 100352   (raw conv out)
    float* sk1 = h1  + 100352;        // 16*32*196      = 100352
    float* h2  = sk1 + 100352;        // 16*16*784      = 200704   (raw conv out)
    float* sk2 = h2  + 200704;        // 16*16*784      = 200704
    float* h3  = sk2 + 200704;        // 16*8*3136      = 401408   (raw conv out)
    float* h4  = h3  + 401408;        // 16*4*12544     = 802816   (raw conv out)
    float* pre = h4  + 802816;        // 16*2*50176     = 1605632
    float* st1 = pre + 1605632;       // 16*8*2  = 256
    float* st2 = st1 + 256;           // 16*4*2  = 128
    float* st3 = st2 + 128;           // 16*2*2  = 64
    float* st4 = st3 + 64;            // 16*1*2  = 32

    // ---- SIFT features ----
    sift_kernel<32, 7, 256><<<784,   256, 0, stream>>>(x, s7);
    sift_kernel<16,14, 256><<<3136,  256, 0, stream>>>(x, s14);
    sift_kernel< 8,28, 128><<<12544, 128, 0, stream>>>(x, s28);

    zero_stats<<<2, 256, 0, stream>>>(st1, 480);

    // ---- skip connections ----
    conv1x1<32, 196><<<98,  256, 0, stream>>>(s14, s1w, s1b, sk1);
    conv1x1<16, 784><<<196, 256, 0, stream>>>(s28, s2w, s2b, sk2);

    // L1: convT(128->32, 7->14), GN(8). NCH=4 -> CB=8, RT=14 (full). grid (1, 128).
    convt_tiled<128, 0, 32, 8,  7, 4, 14, 256, false, 1, 1>
        <<<dim3(1, 16*8), 256, 0, stream>>>(s7, nullptr, d1w, d1b, nullptr, nullptr, nullptr, h1, st1);
    // L2: convT(64->16, 14->28), GN(4). in0=h1 via GN(8,784). NCH=8 -> CB=2, RT=4. grid (7, 32), 128 thr.
    convt_tiled< 32,32, 16, 4, 14, 8,  4, 128, true, 8, 784>
        <<<dim3(7, 16*2), 128, 0, stream>>>(h1, sk1, d2w, d2b, st1, g1w, g1b, h2, st2);
    // L3: convT(32->8, 28->56), GN(2). in0=h2 via GN(4,3136). NCH=8 -> CB=1, RT=4. grid (14, 16).
    convt_tiled< 16,16,  8, 2, 28, 8,  4, 256, true, 4, 3136>
        <<<dim3(14, 16), 256, 0, stream>>>(h2, sk2, d3w, d3b, st2, g2w, g2b, h3, st3);
    // L4: convT(8->4, 56->112), GN(1). in0=h3 via GN(2,12544). NCH=4 -> CB=1, RT=2. grid (56, 16).
    convt_tiled<  8, 0,  4, 1, 56, 4,  2, 256, true, 2, 12544>
        <<<dim3(56, 16), 256, 0, stream>>>(h3, nullptr, d4w, d4b, st3, g3w, g3b, h4, st4);

    // head: final convT reads h4 via GN(1, NG=50176)
    convt_final_fused<<<dim3(196, 16), 256, 0, stream>>>(h4, fw, fb, st4, g4w, g4b, pre);
    bilateral_tanh<<<3136, 256, 0, stream>>>(x, pre, out);
}

// Round 6
// 270.030 us; speedup vs baseline: 6.7898x; 1.3387x over previous
//
#include <hip/hip_runtime.h>
#include <math.h>

#define PI_F 3.14159265358979323846f

// ======================= SIFT descriptor =======================
template<int PS, int K, int NT>
__global__ __launch_bounds__(NT)
void sift_kernel(const float* __restrict__ x, float* __restrict__ out)
{
    constexpr int NPIX = PS*PS;
    constexpr int BK = 2*(PS/5);
    constexpr int STRIDE = PS/4;
    constexpr int PAD = BK/4;
    constexpr float HALF = BK*0.5f;

    __shared__ float patch[NPIX];
    __shared__ float bins[8*NPIX];
    __shared__ float g1[PS];
    __shared__ float desc[128];
    __shared__ float red[NT];
    __shared__ float gsum_s;

    const int tid = threadIdx.x;
    const int n = blockIdx.x;
    const int b = n / (K*K);
    const int c = n % (K*K);
    const int ki = c / K;
    const int kj = c % K;

    const float* xb = x + (size_t)b*224*224;
    for (int idx = tid; idx < NPIX; idx += NT) {
        int i = idx / PS, j = idx - i*PS;
        patch[idx] = xb[(i*K + ki)*224 + (j*K + kj)];
    }
    if (tid < PS) {
        const float sigma = (float)PS * 0.70710678118654752440f;
        float xv = (float)tid - (PS-1)*0.5f;
        float t = xv / sigma;
        g1[tid] = expf(-0.5f*t*t);
    }
    for (int idx = tid; idx < 8*NPIX; idx += NT) bins[idx] = 0.f;
    __syncthreads();
    if (tid == 0) {
        float s = 0.f;
        for (int i = 0; i < PS; i++) s += g1[i];
        gsum_s = s;
    }
    __syncthreads();
    const float ginv = 1.0f / (gsum_s*gsum_s);

    for (int idx = tid; idx < NPIX; idx += NT) {
        int i = idx / PS, j = idx - i*PS;
        int jm = j > 0 ? j-1 : 0, jp = j < PS-1 ? j+1 : PS-1;
        int im = i > 0 ? i-1 : 0, ip = i < PS-1 ? i+1 : PS-1;
        float gx = 0.5f*(patch[i*PS+jp] - patch[i*PS+jm]);
        float gy = 0.5f*(patch[ip*PS+j] - patch[im*PS+j]);
        float mag = sqrtf(gx*gx + gy*gy + 1e-10f) * (g1[i]*g1[j]*ginv);
        float ori = atan2f(gy, gx + 1e-10f) + 2.f*PI_F;
        float obig = ori * (8.f/(2.f*PI_F));
        float bo0f = floorf(obig);
        float w1 = obig - bo0f;
        int bo0 = ((int)bo0f) & 7;
        int bo1 = (bo0 + 1) & 7;
        bins[bo0*NPIX + idx] = (1.f - w1)*mag;
        bins[bo1*NPIX + idx] = w1*mag;
    }
    __syncthreads();

    for (int t = tid; t < 128; t += NT) {
        int o = t >> 4;
        int py = (t >> 2) & 3;
        int px = t & 3;
        int sy = py*STRIDE - PAD;
        int sx = px*STRIDE - PAD;
        const float* bo = bins + o*NPIX;
        float acc = 0.f;
        for (int di = 0; di < BK; di++) {
            int i = sy + di;
            if (i < 0 || i >= PS) continue;
            float wi = HALF - fabsf((float)di + 0.5f - HALF);
            for (int dj = 0; dj < BK; dj++) {
                int j = sx + dj;
                if (j < 0 || j >= PS) continue;
                float wj = HALF - fabsf((float)dj + 0.5f - HALF);
                acc += bo[i*PS + j] * (wi*wj);
            }
        }
        desc[t] = acc * (1.0f/(HALF*HALF));
    }
    __syncthreads();

    float d = (tid < 128) ? desc[tid] : 0.f;
    red[tid] = d*d; __syncthreads();
    for (int s = NT/2; s > 0; s >>= 1) { if (tid < s) red[tid] += red[tid+s]; __syncthreads(); }
    float nrm = sqrtf(red[0]); __syncthreads();
    d = d / fmaxf(nrm, 1e-12f);
    d = fminf(fmaxf(d, 0.f), 0.2f);
    red[tid] = d*d; __syncthreads();
    for (int s = NT/2; s > 0; s >>= 1) { if (tid < s) red[tid] += red[tid+s]; __syncthreads(); }
    nrm = sqrtf(red[0]); __syncthreads();
    d = d / fmaxf(nrm, 1e-12f);
    red[tid] = d; __syncthreads();
    for (int s = NT/2; s > 0; s >>= 1) { if (tid < s) red[tid] += red[tid+s]; __syncthreads(); }
    float ssum = red[0];
    d = sqrtf(d / fmaxf(ssum, 1e-12f) + 1e-10f);
    if (tid < 128) out[(size_t)n*128 + tid] = d;
}

// ====== ConvTranspose2d(k4,s2,p1) via LDS tile [+GN-on-read] -> partial GN stats ======
// Block = (b, channel-block cb, row-tile bx). NO atomics: each block writes its
// partial (sum,sumsq) per covered group to a unique float2 slot; the consumer
// reduces NBLK_IN partials while building its GN coefficients.
template<int CIN0, int CIN1, int COUT, int G, int HIN, int NCH, int RT, int NT,
         bool FUSE, int GIN, int NGIN, int NBLK_IN, int NBLK_OUT>
__global__ __launch_bounds__(NT)
void convt_tiled(const float* __restrict__ in0, const float* __restrict__ in1,
                 const float* __restrict__ w, const float* __restrict__ bias,
                 const float2* __restrict__ pst_in,
                 const float* __restrict__ gnw, const float* __restrict__ gnb,
                 float* __restrict__ out, float2* __restrict__ pst_out)
{
    constexpr int CIN = CIN0 + CIN1;
    constexpr int CG = COUT / G;
    constexpr int NGRP = NCH / CG;
    constexpr int CB = COUT / NCH;
    constexpr int H0 = 2*HIN;
    constexpr int SP = H0*H0;
    constexpr int HIN2 = HIN*HIN;
    constexpr int NR = RT/2 + 2;
    constexpr int WIN = HIN + 2;
    constexpr int TILE = CIN*NR*WIN;
    constexpr int WSTRIDE = CIN*NCH*4 + 4;
    constexpr int NPOS = RT*H0;
    constexpr int NWAVE = NT/64;

    __shared__ float tile[TILE];
    __shared__ float wl2[4*WSTRIDE];
    __shared__ float a_s[CIN0];
    __shared__ float b_s[CIN0];
    __shared__ float wpart[NWAVE][NGRP][2];

    const int tid = threadIdx.x;
    const int by = blockIdx.y;
    const int bx = blockIdx.x;
    const int b  = by / CB;
    const int cb = by - b*CB;
    const int c0 = cb*NCH;
    const int g0 = c0 / CG;
    const int r0 = bx * RT;
    const int row0 = r0/2 - 1;

    if constexpr (FUSE) {
        if (tid < CIN0) {
            int gi = tid / (CIN0/GIN);
            float s0 = 0.f, s1 = 0.f;
            for (int k = 0; k < NBLK_IN; k++) {
                float2 p = pst_in[((size_t)b*GIN + gi)*NBLK_IN + k];
                s0 += p.x; s1 += p.y;
            }
            float mean = s0 * (1.f/NGIN);
            float var  = s1 * (1.f/NGIN) - mean*mean;
            float inv  = rsqrtf(var + 1e-5f);
            float a = inv * gnw[tid];
            a_s[tid] = a;
            b_s[tid] = gnb[tid] - mean*a;
        }
        __syncthreads();
    }

    // stage parity-permuted weights
    for (int idx = tid; idx < 4*CIN*NCH*4; idx += NT) {
        int k = idx & 3;
        int t2 = idx >> 2;
        int j = t2 % NCH; t2 /= NCH;
        int ci = t2 % CIN;
        int pq = t2 / CIN;
        int pA = pq >> 1, qA = pq & 1;
        int dy = pA + 2*(k>>1), dx = qA + 2*(k&1);
        wl2[pq*WSTRIDE + (ci*NCH + j)*4 + k] = w[(ci*COUT + c0 + j)*16 + dy*4 + dx];
    }

    // stage zero-padded input tile (GN+ReLU applied to in0 channels if FUSE)
    const float* i0 = in0 + (size_t)b*CIN0*HIN2;
    for (int idx = tid; idx < TILE; idx += NT) {
        int c = idx % WIN;
        int t2 = idx / WIN;
        int r = t2 % NR;
        int ci = t2 / NR;
        int iy = row0 + r, ix = c - 1;
        float v = 0.f;
        if (iy >= 0 && iy < HIN && ix >= 0 && ix < HIN) {
            if (CIN1 == 0 || ci < CIN0) {
                v = i0[ci*HIN2 + iy*HIN + ix];
                if constexpr (FUSE) v = fmaxf(v*a_s[ci] + b_s[ci], 0.f);
            } else {
                v = in1[((size_t)b*CIN1 + (ci-CIN0))*HIN2 + iy*HIN + ix];
            }
        }
        tile[idx] = v;
    }
    __syncthreads();

    float acc[NCH];
    #pragma unroll
    for (int j = 0; j < NCH; j++) acc[j] = 0.f;

    const bool active = tid < NPOS;
    if (active) {
        int oy = r0 + tid / H0, ox = tid % H0;
        int pA = (oy+1)&1, qA = (ox+1)&1;
        int iyA = (oy+1-pA)>>1, ixA = (ox+1-qA)>>1;
        int rA = iyA - row0;
        int cA = ixA + 1;
        int toff = rA*WIN + cA;
        const float* wbase = wl2 + (pA*2+qA)*WSTRIDE;

        #pragma unroll
        for (int j = 0; j < NCH; j++) acc[j] = bias[c0 + j];

        #pragma unroll 4
        for (int ci = 0; ci < CIN; ci++) {
            const float* tp = tile + ci*(NR*WIN) + toff;
            float l0 = tp[0];
            float l1 = tp[-1];
            float l2 = tp[-WIN];
            float l3 = tp[-WIN-1];
            const float* wr = wbase + ci*NCH*4;
            #pragma unroll
            for (int j = 0; j < NCH; j++) {
                const float4 wv = *(const float4*)(wr + j*4);
                acc[j] += l0*wv.x + l1*wv.y + l2*wv.z + l3*wv.w;
            }
        }
        float* ob = out + ((size_t)b*COUT + c0)*SP + r0*H0 + tid;
        #pragma unroll
        for (int j = 0; j < NCH; j++) ob[j*SP] = acc[j];
    }

    // block-level stats reduce: wave shuffle -> LDS -> one float2 store per group
    const int wv = tid >> 6;
    const int ln = tid & 63;
    #pragma unroll
    for (int grp = 0; grp < NGRP; grp++) {
        float ps = 0.f, pq2 = 0.f;
        #pragma unroll
        for (int j = 0; j < CG; j++) {
            float v = active ? acc[grp*CG + j] : 0.f;
            ps += v; pq2 += v*v;
        }
        #pragma unroll
        for (int off = 32; off > 0; off >>= 1) {
            ps  += __shfl_down(ps,  off);
            pq2 += __shfl_down(pq2, off);
        }
        if (ln == 0) { wpart[wv][grp][0] = ps; wpart[wv][grp][1] = pq2; }
    }
    __syncthreads();
    if (tid < NGRP) {
        float s0 = 0.f, s1 = 0.f;
        #pragma unroll
        for (int w2 = 0; w2 < NWAVE; w2++) { s0 += wpart[w2][tid][0]; s1 += wpart[w2][tid][1]; }
        pst_out[((size_t)b*G + g0 + tid)*NBLK_OUT + bx] = make_float2(s0, s1);
    }
}

// ======================= 1x1 conv, 4 outputs/thread =======================
template<int CO, int S>
__global__ __launch_bounds__(256)
void conv1x1(const float* __restrict__ in, const float* __restrict__ w,
             const float* __restrict__ bias, float* __restrict__ out)
{
    __shared__ float wt[128*CO];   // transposed: wt[c*CO + co]
    const int tid = threadIdx.x;
    for (int i = tid; i < 128*CO; i += 256) {
        int c = i / CO, co = i - c*CO;
        wt[i] = w[co*128 + c];
    }
    __syncthreads();
    int idx = blockIdx.x*256 + tid;         // 16 * (CO/4) * S threads exactly
    int s = idx % S; int r = idx / S;
    int co4 = r % (CO/4); int b = r / (CO/4);
    int co = co4*4;
    const float* ib = in + (size_t)b*128*S + s;
    float acc0 = bias[co], acc1 = bias[co+1], acc2 = bias[co+2], acc3 = bias[co+3];
    #pragma unroll 8
    for (int c = 0; c < 128; c++) {
        float v = ib[c*S];
        const float4 wv = *(const float4*)&wt[c*CO + co];
        acc0 += v*wv.x; acc1 += v*wv.y; acc2 += v*wv.z; acc3 += v*wv.w;
    }
    float* ob = out + ((size_t)b*CO + co)*S + s;
    ob[0] = acc0; ob[S] = acc1; ob[2*S] = acc2; ob[3*S] = acc3;
}

// ======= final ConvTranspose2d (4->2) with GN-on-read of h4 (56 partials) =======
__global__ __launch_bounds__(256)
void convt_final_fused(const float* __restrict__ in, const float* __restrict__ w,
                       const float* __restrict__ bias,
                       const float2* __restrict__ pst_in,
                       const float* __restrict__ gnw, const float* __restrict__ gnb,
                       float* __restrict__ out)
{
    __shared__ float wl2[128];   // wl2[((pq*4+ci)*2+co)*4+k]
    __shared__ float a_s[4], b_s[4], bl[2], mv[2];
    const int tid = threadIdx.x;
    const int b = blockIdx.y;
    if (tid < 128) {
        int k = tid & 3;
        int t = tid >> 2;
        int co = t & 1; t >>= 1;
        int ci = t & 3;
        int pq = t >> 2;
        int pA = pq >> 1, qA = pq & 1;
        int dy = pA + 2*(k>>1), dx = qA + 2*(k&1);
        wl2[tid] = w[(ci*2 + co)*16 + dy*4 + dx];
    }
    if (tid < 2) bl[tid] = bias[tid];
    // reduce the 56 L4 partials with the first wave
    if (tid < 64) {
        float s0 = 0.f, s1 = 0.f;
        for (int k = tid; k < 56; k += 64) {
            float2 p = pst_in[(size_t)b*56 + k];
            s0 += p.x; s1 += p.y;
        }
        #pragma unroll
        for (int off = 32; off > 0; off >>= 1) {
            s0 += __shfl_down(s0, off);
            s1 += __shfl_down(s1, off);
        }
        if (tid == 0) {
            float mean = s0 * (1.f/50176.f);
            float var  = s1 * (1.f/50176.f) - mean*mean;
            mv[0] = mean;
            mv[1] = rsqrtf(var + 1e-5f);
        }
    }
    __syncthreads();
    if (tid < 4) {
        float a = mv[1] * gnw[tid];
        a_s[tid] = a;
        b_s[tid] = gnb[tid] - mv[0]*a;
    }
    __syncthreads();

    int e = blockIdx.x*256 + tid;           // < 50176 exactly (196 blocks)
    int oy = e / 224, ox = e - oy*224;
    int pA = (oy+1)&1, iyA = (oy+1-pA)>>1, iyB = iyA-1;
    int qA = (ox+1)&1, ixA = (ox+1-qA)>>1, ixB = ixA-1;
    float mYA = (iyA < 112) ? 1.f : 0.f;
    float mYB = (iyB >= 0)  ? 1.f : 0.f;
    float mXA = (ixA < 112) ? 1.f : 0.f;
    float mXB = (ixB >= 0)  ? 1.f : 0.f;
    float m0 = mYA*mXA, m1 = mYA*mXB, m2 = mYB*mXA, m3 = mYB*mXB;
    int iyAc = min(iyA, 111), iyBc = max(iyB, 0);
    int ixAc = min(ixA, 111), ixBc = max(ixB, 0);
    int oAA = iyAc*112 + ixAc, oAB = iyAc*112 + ixBc;
    int oBA = iyBc*112 + ixAc, oBB = iyBc*112 + ixBc;
    const float* wbase = wl2 + (pA*2+qA)*32;

    float acc0 = bl[0], acc1 = bl[1];
    const float* ib = in + (size_t)b*4*112*112;
    #pragma unroll
    for (int ci = 0; ci < 4; ci++) {
        const float* ip = ib + ci*112*112;
        float a = a_s[ci], bb = b_s[ci];
        float l0 = fmaxf(ip[oAA]*a + bb, 0.f);
        float l1 = fmaxf(ip[oAB]*a + bb, 0.f);
        float l2 = fmaxf(ip[oBA]*a + bb, 0.f);
        float l3 = fmaxf(ip[oBB]*a + bb, 0.f);
        float t0 = l0*m0, t1 = l1*m1, t2 = l2*m2, t3 = l3*m3;
        const float4 w0 = *(const float4*)(wbase + ci*8);
        const float4 w1 = *(const float4*)(wbase + ci*8 + 4);
        acc0 += t0*w0.x + t1*w0.y + t2*w0.z + t3*w0.w;
        acc1 += t0*w1.x + t1*w1.y + t2*w1.z + t3*w1.w;
    }
    float* ob = out + (size_t)b*2*50176 + e;
    ob[0] = acc0;
    ob[50176] = acc1;
}

// ============== joint bilateral (5x5, l1 color on guide=x) + tanh*scale ==============
__global__ __launch_bounds__(256)
void bilateral_tanh(const float* __restrict__ x, const float* __restrict__ pre,
                    float* __restrict__ out)
{
    const float g[5] = {0.1200783f, 0.2338817f, 0.2920800f, 0.2338817f, 0.1200783f};
    int idx = blockIdx.x*256 + threadIdx.x;    // 16*224*224 = 802816 exactly
    int px = idx % 224; int r = idx / 224;
    int py = r % 224; int b = r / 224;
    int s = py*224 + px;
    const float* xb = x + (size_t)b*50176;
    const float* p0 = pre + (size_t)b*2*50176;
    const float* p1 = p0 + 50176;
    float center = xb[s];
    float wsum = 0.f, a0 = 0.f, a1 = 0.f;
    #pragma unroll
    for (int di = -2; di <= 2; di++){
        int yy = py + di; yy = yy < 0 ? -yy : (yy > 223 ? 446 - yy : yy);
        #pragma unroll
        for (int dj = -2; dj <= 2; dj++){
            int xx = px + dj; xx = xx < 0 ? -xx : (xx > 223 ? 446 - xx : xx);
            int o = yy*224 + xx;
            float dg = xb[o] - center;
            float wgt = g[di+2]*g[dj+2]*__expf(-200.f*dg*dg);
            wsum += wgt;
            a0 += wgt * p0[o];
            a1 += wgt * p1[o];
        }
    }
    float inv = 1.0f / wsum;
    out[(size_t)(b*2)*50176 + s]     = tanhf(a0*inv)*0.436f;
    out[(size_t)(b*2+1)*50176 + s]   = tanhf(a1*inv)*0.615f;
}

// ======================= launch =======================
extern "C" void kernel_launch(void* const* d_in, const int* in_sizes, int n_in,
                              void* d_out, int out_size, void* d_ws, size_t ws_size,
                              hipStream_t stream) {
    (void)in_sizes; (void)n_in; (void)out_size; (void)ws_size;
    const float* x   = (const float*)d_in[0];
    const float* d1w = (const float*)d_in[1];
    const float* d1b = (const float*)d_in[2];
    const float* g1w = (const float*)d_in[3];
    const float* g1b = (const float*)d_in[4];
    const float* s1w = (const float*)d_in[5];
    const float* s1b = (const float*)d_in[6];
    const float* d2w = (const float*)d_in[7];
    const float* d2b = (const float*)d_in[8];
    const float* g2w = (const float*)d_in[9];
    const float* g2b = (const float*)d_in[10];
    const float* s2w = (const float*)d_in[11];
    const float* s2b = (const float*)d_in[12];
    const float* d3w = (const float*)d_in[13];
    const float* d3b = (const float*)d_in[14];
    const float* g3w = (const float*)d_in[15];
    const float* g3b = (const float*)d_in[16];
    const float* d4w = (const float*)d_in[17];
    const float* d4b = (const float*)d_in[18];
    const float* g4w = (const float*)d_in[19];
    const float* g4b = (const float*)d_in[20];
    const float* fw  = (const float*)d_in[21];
    const float* fb  = (const float*)d_in[22];
    float* out = (float*)d_out;

    float* ws  = (float*)d_ws;
    float* s7  = ws;                  // 16*128*49      = 100352
    float* s14 = s7  + 100352;        // 16*128*196     = 401408
    float* s28 = s14 + 401408;        // 16*128*784     = 1605632
    float* h1  = s28 + 1605632;       // 16*32*196      = 100352   (raw conv out)
    float* sk1 = h1  + 100352;        // 16*32*196      = 100352
    float* h2  = sk1 + 100352;        // 16*16*784      = 200704   (raw conv out)
    float* sk2 = h2  + 200704;        // 16*16*784      = 200704
    float* h3  = sk2 + 200704;        // 16*8*3136      = 401408   (raw conv out)
    float* h4  = h3  + 401408;        // 16*4*12544     = 802816   (raw conv out)
    float* pre = h4  + 802816;        // 16*2*50176     = 1605632
    float2* pst1 = (float2*)(pre + 1605632);   // 16*8  * 1  = 128 pairs
    float2* pst2 = pst1 + 128;                 // 16*4  * 7  = 448 pairs
    float2* pst3 = pst2 + 448;                 // 16*2  * 14 = 448 pairs
    float2* pst4 = pst3 + 448;                 // 16*1  * 56 = 896 pairs

    // ---- SIFT features ----
    sift_kernel<32, 7, 256><<<784,   256, 0, stream>>>(x, s7);
    sift_kernel<16,14, 256><<<3136,  256, 0, stream>>>(x, s14);
    sift_kernel< 8,28, 128><<<12544, 128, 0, stream>>>(x, s28);

    // ---- skip connections ----
    conv1x1<32, 196><<<98,  256, 0, stream>>>(s14, s1w, s1b, sk1);
    conv1x1<16, 784><<<196, 256, 0, stream>>>(s28, s2w, s2b, sk2);

    // L1: convT(128->32, 7->14), GN(8). NCH=4=CG -> one block per (b,g). NBLK_OUT=1.
    convt_tiled<128, 0, 32, 8,  7, 4, 14, 256, false, 1, 1, 1, 1>
        <<<dim3(1, 16*8), 256, 0, stream>>>(s7, nullptr, d1w, d1b, nullptr, nullptr, nullptr, h1, pst1);
    // L2: convT(64->16, 14->28), GN(4). in via GN(8,784,NBLK_IN=1). grid (7,32). NBLK_OUT=7.
    convt_tiled< 32,32, 16, 4, 14, 8,  4, 128, true, 8, 784, 1, 7>
        <<<dim3(7, 16*2), 128, 0, stream>>>(h1, sk1, d2w, d2b, pst1, g1w, g1b, h2, pst2);
    // L3: convT(32->8, 28->56), GN(2). in via GN(4,3136,NBLK_IN=7). grid (14,16). NBLK_OUT=14.
    convt_tiled< 16,16,  8, 2, 28, 8,  4, 256, true, 4, 3136, 7, 14>
        <<<dim3(14, 16), 256, 0, stream>>>(h2, sk2, d3w, d3b, pst2, g2w, g2b, h3, pst3);
    // L4: convT(8->4, 56->112), GN(1). in via GN(2,12544,NBLK_IN=14). grid (56,16). NBLK_OUT=56.
    convt_tiled<  8, 0,  4, 1, 56, 4,  2, 256, true, 2, 12544, 14, 56>
        <<<dim3(56, 16), 256, 0, stream>>>(h3, nullptr, d4w, d4b, pst3, g3w, g3b, h4, pst4);

    // head: final convT reads h4 via GN(1, 50176, 56 partials)
    convt_final_fused<<<dim3(196, 16), 256, 0, stream>>>(h4, fw, fb, pst4, g4w, g4b, pre);
    bilateral_tanh<<<3136, 256, 0, stream>>>(x, pre, out);
}

// Round 8
// 247.493 us; speedup vs baseline: 7.4081x; 1.0911x over previous
//
#include <hip/hip_runtime.h>
#include <math.h>

#define PI_F 3.14159265358979323846f

// ======================= SIFT descriptor =======================
// One block per patch (stride-K subsample of the image):
// patch[i][j] = x[b, i*K+ki, j*K+kj], n = b*K*K + (ki*K+kj).
// Output written FLAT: out[n*128 + d]. NOTE: the reference's reshape
// (B*K*K,128)->(B,128,K,K) is a raw reinterpretation (scrambles patch/desc
// axes since 128 != K*K); consumers must read the same flat layout (B,128,K*K).
template<int PS, int K, int NT>
__global__ __launch_bounds__(NT)
void sift_kernel(const float* __restrict__ x, float* __restrict__ out)
{
    constexpr int NPIX = PS*PS;
    constexpr int BK = 2*(PS/5);
    constexpr int STRIDE = PS/4;
    constexpr int PAD = BK/4;
    constexpr float HALF = BK*0.5f;
    constexpr int NWAVE = NT/64;
    constexpr int HALVES = (NT >= 256) ? 2 : 1;
    constexpr int ROWS = BK / HALVES;

    __shared__ float patch[NPIX];
    __shared__ float bins[8*NPIX];
    __shared__ float g1[PS];
    __shared__ float pool2[128];
    __shared__ float wred[NWAVE];
    __shared__ float gsum_s;

    const int tid = threadIdx.x;
    const int n = blockIdx.x;
    const int b = n / (K*K);
    const int c = n % (K*K);
    const int ki = c / K;
    const int kj = c % K;

    const float* xb = x + (size_t)b*224*224;
    for (int idx = tid; idx < NPIX; idx += NT) {
        int i = idx / PS, j = idx - i*PS;
        patch[idx] = xb[(i*K + ki)*224 + (j*K + kj)];
    }
    if (tid < PS) {
        const float sigma = (float)PS * 0.70710678118654752440f;
        float xv = (float)tid - (PS-1)*0.5f;
        float t = xv / sigma;
        g1[tid] = expf(-0.5f*t*t);
    }
    for (int idx = tid; idx < 8*NPIX; idx += NT) bins[idx] = 0.f;
    __syncthreads();
    if (tid == 0) {
        float s = 0.f;
        for (int i = 0; i < PS; i++) s += g1[i];
        gsum_s = s;
    }
    __syncthreads();
    const float ginv = 1.0f / (gsum_s*gsum_s);

    for (int idx = tid; idx < NPIX; idx += NT) {
        int i = idx / PS, j = idx - i*PS;
        int jm = j > 0 ? j-1 : 0, jp = j < PS-1 ? j+1 : PS-1;
        int im = i > 0 ? i-1 : 0, ip = i < PS-1 ? i+1 : PS-1;
        float gx = 0.5f*(patch[i*PS+jp] - patch[i*PS+jm]);
        float gy = 0.5f*(patch[ip*PS+j] - patch[im*PS+j]);
        float mag = sqrtf(gx*gx + gy*gy + 1e-10f) * (g1[i]*g1[j]*ginv);
        float ori = atan2f(gy, gx + 1e-10f) + 2.f*PI_F;
        float obig = ori * (8.f/(2.f*PI_F));
        float bo0f = floorf(obig);
        float w1 = obig - bo0f;
        int bo0 = ((int)bo0f) & 7;
        int bo1 = (bo0 + 1) & 7;
        bins[bo0*NPIX + idx] = (1.f - w1)*mag;
        bins[bo1*NPIX + idx] = w1*mag;
    }
    __syncthreads();

    // Triangular pooling, split across HALVES thread halves
    float pacc = 0.f;
    const int t = tid & 127;
    const int half = (HALVES == 2) ? (tid >> 7) : 0;
    if (tid < 128*HALVES) {
        int o = t >> 4;
        int py = (t >> 2) & 3;
        int px = t & 3;
        int sy = py*STRIDE - PAD;
        int sx = px*STRIDE - PAD;
        const float* bo = bins + o*NPIX;
        for (int dr = 0; dr < ROWS; dr++) {
            int di = half*ROWS + dr;
            int i = sy + di;
            if (i < 0 || i >= PS) continue;
            float wi = HALF - fabsf((float)di + 0.5f - HALF);
            for (int dj = 0; dj < BK; dj++) {
                int j = sx + dj;
                if (j < 0 || j >= PS) continue;
                float wj = HALF - fabsf((float)dj + 0.5f - HALF);
                pacc += bo[i*PS + j] * (wi*wj);
            }
        }
    }
    if (HALVES == 2) {
        if (half == 1) pool2[t] = pacc;
        __syncthreads();
    }
    float d = 0.f;
    if (tid < 128) {
        d = pacc;
        if (HALVES == 2) d += pool2[tid];
        d *= 1.0f/(HALF*HALF);
    }

    // normalize chain with wave-shuffle reductions
    const int wv = tid >> 6;
    const int ln = tid & 63;

    float v = d*d;
    #pragma unroll
    for (int off = 32; off > 0; off >>= 1) v += __shfl_down(v, off);
    if (ln == 0) wred[wv] = v;
    __syncthreads();
    float nrm = 0.f;
    #pragma unroll
    for (int w2 = 0; w2 < NWAVE; w2++) nrm += wred[w2];
    nrm = sqrtf(nrm);
    __syncthreads();
    d = d / fmaxf(nrm, 1e-12f);
    d = fminf(fmaxf(d, 0.f), 0.2f);

    v = d*d;
    #pragma unroll
    for (int off = 32; off > 0; off >>= 1) v += __shfl_down(v, off);
    if (ln == 0) wred[wv] = v;
    __syncthreads();
    nrm = 0.f;
    #pragma unroll
    for (int w2 = 0; w2 < NWAVE; w2++) nrm += wred[w2];
    nrm = sqrtf(nrm);
    __syncthreads();
    d = d / fmaxf(nrm, 1e-12f);

    v = d;    // d >= 0 -> sum == sum(|d|)
    #pragma unroll
    for (int off = 32; off > 0; off >>= 1) v += __shfl_down(v, off);
    if (ln == 0) wred[wv] = v;
    __syncthreads();
    float ssum = 0.f;
    #pragma unroll
    for (int w2 = 0; w2 < NWAVE; w2++) ssum += wred[w2];
    d = sqrtf(d / fmaxf(ssum, 1e-12f) + 1e-10f);

    if (tid < 128) out[(size_t)n*128 + tid] = d;
}

// ======================= 1x1 conv, 4 outputs/thread =======================
// Reads the flat SIFT buffer as (B,128,S) — matches the reference's reshape.
template<int CO, int S>
__global__ __launch_bounds__(256)
void conv1x1(const float* __restrict__ in, const float* __restrict__ w,
             const float* __restrict__ bias, float* __restrict__ out)
{
    __shared__ float wt[128*CO];   // transposed: wt[c*CO + co]
    const int tid = threadIdx.x;
    for (int i = tid; i < 128*CO; i += 256) {
        int c = i / CO, co = i - c*CO;
        wt[i] = w[co*128 + c];
    }
    __syncthreads();
    int idx = blockIdx.x*256 + tid;         // 16 * (CO/4) * S threads exactly
    int s = idx % S; int r = idx / S;
    int co4 = r % (CO/4); int b = r / (CO/4);
    int co = co4*4;
    const float* ib = in + (size_t)b*128*S + s;
    float acc0 = bias[co], acc1 = bias[co+1], acc2 = bias[co+2], acc3 = bias[co+3];
    #pragma unroll 8
    for (int c = 0; c < 128; c++) {
        float v = ib[c*S];
        const float4 wv = *(const float4*)&wt[c*CO + co];
        acc0 += v*wv.x; acc1 += v*wv.y; acc2 += v*wv.z; acc3 += v*wv.w;
    }
    float* ob = out + ((size_t)b*CO + co)*S + s;
    ob[0] = acc0; ob[S] = acc1; ob[2*S] = acc2; ob[3*S] = acc3;
}

// ====== ConvTranspose2d(k4,s2,p1) via LDS tile [+GN-on-read] -> partial GN stats ======
template<int CIN0, int CIN1, int COUT, int G, int HIN, int NCH, int RT, int NT,
         bool FUSE, int GIN, int NGIN, int NBLK_IN, int NBLK_OUT>
__global__ __launch_bounds__(NT)
void convt_tiled(const float* __restrict__ in0, const float* __restrict__ in1,
                 const float* __restrict__ w, const float* __restrict__ bias,
                 const float2* __restrict__ pst_in,
                 const float* __restrict__ gnw, const float* __restrict__ gnb,
                 float* __restrict__ out, float2* __restrict__ pst_out)
{
    constexpr int CIN = CIN0 + CIN1;
    constexpr int CG = COUT / G;
    constexpr int NGRP = NCH / CG;
    constexpr int CB = COUT / NCH;
    constexpr int H0 = 2*HIN;
    constexpr int SP = H0*H0;
    constexpr int HIN2 = HIN*HIN;
    constexpr int NR = RT/2 + 2;
    constexpr int WIN = HIN + 2;
    constexpr int TILE = CIN*NR*WIN;
    constexpr int WSTRIDE = CIN*NCH*4 + 4;
    constexpr int NPOS = RT*H0;
    constexpr int NWAVE = NT/64;

    __shared__ float tile[TILE];
    __shared__ float wl2[4*WSTRIDE];
    __shared__ float a_s[CIN0];
    __shared__ float b_s[CIN0];
    __shared__ float wpart[NWAVE][NGRP][2];

    const int tid = threadIdx.x;
    const int by = blockIdx.y;
    const int bx = blockIdx.x;
    const int b  = by / CB;
    const int cb = by - b*CB;
    const int c0 = cb*NCH;
    const int g0 = c0 / CG;
    const int r0 = bx * RT;
    const int row0 = r0/2 - 1;

    if constexpr (FUSE) {
        if (tid < CIN0) {
            int gi = tid / (CIN0/GIN);
            float s0 = 0.f, s1 = 0.f;
            for (int k = 0; k < NBLK_IN; k++) {
                float2 p = pst_in[((size_t)b*GIN + gi)*NBLK_IN + k];
                s0 += p.x; s1 += p.y;
            }
            float mean = s0 * (1.f/NGIN);
            float var  = s1 * (1.f/NGIN) - mean*mean;
            float inv  = rsqrtf(var + 1e-5f);
            float a = inv * gnw[tid];
            a_s[tid] = a;
            b_s[tid] = gnb[tid] - mean*a;
        }
        __syncthreads();
    }

    for (int idx = tid; idx < 4*CIN*NCH*4; idx += NT) {
        int k = idx & 3;
        int t2 = idx >> 2;
        int j = t2 % NCH; t2 /= NCH;
        int ci = t2 % CIN;
        int pq = t2 / CIN;
        int pA = pq >> 1, qA = pq & 1;
        int dy = pA + 2*(k>>1), dx = qA + 2*(k&1);
        wl2[pq*WSTRIDE + (ci*NCH + j)*4 + k] = w[(ci*COUT + c0 + j)*16 + dy*4 + dx];
    }

    const float* i0 = in0 + (size_t)b*CIN0*HIN2;
    for (int idx = tid; idx < TILE; idx += NT) {
        int c = idx % WIN;
        int t2 = idx / WIN;
        int r = t2 % NR;
        int ci = t2 / NR;
        int iy = row0 + r, ix = c - 1;
        float v = 0.f;
        if (iy >= 0 && iy < HIN && ix >= 0 && ix < HIN) {
            if (CIN1 == 0 || ci < CIN0) {
                v = i0[ci*HIN2 + iy*HIN + ix];
                if constexpr (FUSE) v = fmaxf(v*a_s[ci] + b_s[ci], 0.f);
            } else {
                v = in1[((size_t)b*CIN1 + (ci-CIN0))*HIN2 + iy*HIN + ix];
            }
        }
        tile[idx] = v;
    }
    __syncthreads();

    float acc[NCH];
    #pragma unroll
    for (int j = 0; j < NCH; j++) acc[j] = 0.f;

    const bool active = tid < NPOS;
    if (active) {
        int oy = r0 + tid / H0, ox = tid % H0;
        int pA = (oy+1)&1, qA = (ox+1)&1;
        int iyA = (oy+1-pA)>>1, ixA = (ox+1-qA)>>1;
        int rA = iyA - row0;
        int cA = ixA + 1;
        int toff = rA*WIN + cA;
        const float* wbase = wl2 + (pA*2+qA)*WSTRIDE;

        #pragma unroll
        for (int j = 0; j < NCH; j++) acc[j] = bias[c0 + j];

        #pragma unroll 4
        for (int ci = 0; ci < CIN; ci++) {
            const float* tp = tile + ci*(NR*WIN) + toff;
            float l0 = tp[0];
            float l1 = tp[-1];
            float l2 = tp[-WIN];
            float l3 = tp[-WIN-1];
            const float* wr = wbase + ci*NCH*4;
            #pragma unroll
            for (int j = 0; j < NCH; j++) {
                const float4 wv = *(const float4*)(wr + j*4);
                acc[j] += l0*wv.x + l1*wv.y + l2*wv.z + l3*wv.w;
            }
        }
        float* ob = out + ((size_t)b*COUT + c0)*SP + r0*H0 + tid;
        #pragma unroll
        for (int j = 0; j < NCH; j++) ob[j*SP] = acc[j];
    }

    const int wv = tid >> 6;
    const int ln = tid & 63;
    #pragma unroll
    for (int grp = 0; grp < NGRP; grp++) {
        float ps = 0.f, pq2 = 0.f;
        #pragma unroll
        for (int j = 0; j < CG; j++) {
            float v = active ? acc[grp*CG + j] : 0.f;
            ps += v; pq2 += v*v;
        }
        #pragma unroll
        for (int off = 32; off > 0; off >>= 1) {
            ps  += __shfl_down(ps,  off);
            pq2 += __shfl_down(pq2, off);
        }
        if (ln == 0) { wpart[wv][grp][0] = ps; wpart[wv][grp][1] = pq2; }
    }
    __syncthreads();
    if (tid < NGRP) {
        float s0 = 0.f, s1 = 0.f;
        #pragma unroll
        for (int w2 = 0; w2 < NWAVE; w2++) { s0 += wpart[w2][tid][0]; s1 += wpart[w2][tid][1]; }
        pst_out[((size_t)b*G + g0 + tid)*NBLK_OUT + bx] = make_float2(s0, s1);
    }
}

// ======= final ConvTranspose2d (4->2) with GN-on-read of h4 (56 partials) =======
__global__ __launch_bounds__(256)
void convt_final_fused(const float* __restrict__ in, const float* __restrict__ w,
                       const float* __restrict__ bias,
                       const float2* __restrict__ pst_in,
                       const float* __restrict__ gnw, const float* __restrict__ gnb,
                       float* __restrict__ out)
{
    __shared__ float wl2[128];
    __shared__ float a_s[4], b_s[4], bl[2], mv[2];
    const int tid = threadIdx.x;
    const int b = blockIdx.y;
    if (tid < 128) {
        int k = tid & 3;
        int t = tid >> 2;
        int co = t & 1; t >>= 1;
        int ci = t & 3;
        int pq = t >> 2;
        int pA = pq >> 1, qA = pq & 1;
        int dy = pA + 2*(k>>1), dx = qA + 2*(k&1);
        wl2[tid] = w[(ci*2 + co)*16 + dy*4 + dx];
    }
    if (tid < 2) bl[tid] = bias[tid];
    if (tid < 64) {
        float s0 = 0.f, s1 = 0.f;
        for (int k = tid; k < 56; k += 64) {
            float2 p = pst_in[(size_t)b*56 + k];
            s0 += p.x; s1 += p.y;
        }
        #pragma unroll
        for (int off = 32; off > 0; off >>= 1) {
            s0 += __shfl_down(s0, off);
            s1 += __shfl_down(s1, off);
        }
        if (tid == 0) {
            float mean = s0 * (1.f/50176.f);
            float var  = s1 * (1.f/50176.f) - mean*mean;
            mv[0] = mean;
            mv[1] = rsqrtf(var + 1e-5f);
        }
    }
    __syncthreads();
    if (tid < 4) {
        float a = mv[1] * gnw[tid];
        a_s[tid] = a;
        b_s[tid] = gnb[tid] - mv[0]*a;
    }
    __syncthreads();

    int e = blockIdx.x*256 + tid;
    int oy = e / 224, ox = e - oy*224;
    int pA = (oy+1)&1, iyA = (oy+1-pA)>>1, iyB = iyA-1;
    int qA = (ox+1)&1, ixA = (ox+1-qA)>>1, ixB = ixA-1;
    float mYA = (iyA < 112) ? 1.f : 0.f;
    float mYB = (iyB >= 0)  ? 1.f : 0.f;
    float mXA = (ixA < 112) ? 1.f : 0.f;
    float mXB = (ixB >= 0)  ? 1.f : 0.f;
    float m0 = mYA*mXA, m1 = mYA*mXB, m2 = mYB*mXA, m3 = mYB*mXB;
    int iyAc = min(iyA, 111), iyBc = max(iyB, 0);
    int ixAc = min(ixA, 111), ixBc = max(ixB, 0);
    int oAA = iyAc*112 + ixAc, oAB = iyAc*112 + ixBc;
    int oBA = iyBc*112 + ixAc, oBB = iyBc*112 + ixBc;
    const float* wbase = wl2 + (pA*2+qA)*32;

    float acc0 = bl[0], acc1 = bl[1];
    const float* ib = in + (size_t)b*4*112*112;
    #pragma unroll
    for (int ci = 0; ci < 4; ci++) {
        const float* ip = ib + ci*112*112;
        float a = a_s[ci], bb = b_s[ci];
        float l0 = fmaxf(ip[oAA]*a + bb, 0.f);
        float l1 = fmaxf(ip[oAB]*a + bb, 0.f);
        float l2 = fmaxf(ip[oBA]*a + bb, 0.f);
        float l3 = fmaxf(ip[oBB]*a + bb, 0.f);
        float t0 = l0*m0, t1 = l1*m1, t2 = l2*m2, t3 = l3*m3;
        const float4 w0 = *(const float4*)(wbase + ci*8);
        const float4 w1 = *(const float4*)(wbase + ci*8 + 4);
        acc0 += t0*w0.x + t1*w0.y + t2*w0.z + t3*w0.w;
        acc1 += t0*w1.x + t1*w1.y + t2*w1.z + t3*w1.w;
    }
    float* ob = out + (size_t)b*2*50176 + e;
    ob[0] = acc0;
    ob[50176] = acc1;
}

// ====== joint bilateral (5x5, guide=x) + tanh*scale, LDS-tiled 16x16 ======
__global__ __launch_bounds__(256)
void bilateral_tiled(const float* __restrict__ x, const float* __restrict__ pre,
                     float* __restrict__ out)
{
    const float g[5] = {0.1200783f, 0.2338817f, 0.2920800f, 0.2338817f, 0.1200783f};
    __shared__ float xs[400], p0s[400], p1s[400];   // 20x20 tiles

    const int tid = threadIdx.x;
    const int b = blockIdx.z;
    const int ty0 = blockIdx.y*16;
    const int tx0 = blockIdx.x*16;
    const float* xb = x + (size_t)b*50176;
    const float* p0 = pre + (size_t)b*2*50176;
    const float* p1 = p0 + 50176;

    for (int idx = tid; idx < 400; idx += 256) {
        int r = idx / 20, cc = idx - r*20;
        int gy = ty0 - 2 + r;  gy = gy < 0 ? -gy : (gy > 223 ? 446 - gy : gy);
        int gx = tx0 - 2 + cc; gx = gx < 0 ? -gx : (gx > 223 ? 446 - gx : gx);
        int o = gy*224 + gx;
        xs[idx]  = xb[o];
        p0s[idx] = p0[o];
        p1s[idx] = p1[o];
    }
    __syncthreads();

    int ly = tid >> 4, lx = tid & 15;
    int base = (ly+2)*20 + (lx+2);
    float center = xs[base];
    float wsum = 0.f, a0 = 0.f, a1 = 0.f;
    #pragma unroll
    for (int di = -2; di <= 2; di++){
        #pragma unroll
        for (int dj = -2; dj <= 2; dj++){
            int o = base + di*20 + dj;
            float dg = xs[o] - center;
            float wgt = g[di+2]*g[dj+2]*__expf(-200.f*dg*dg);
            wsum += wgt;
            a0 += wgt * p0s[o];
            a1 += wgt * p1s[o];
        }
    }
    float inv = 1.0f / wsum;
    int s = (ty0 + ly)*224 + (tx0 + lx);
    out[(size_t)(b*2)*50176 + s]     = tanhf(a0*inv)*0.436f;
    out[(size_t)(b*2+1)*50176 + s]   = tanhf(a1*inv)*0.615f;
}

// ======================= launch =======================
extern "C" void kernel_launch(void* const* d_in, const int* in_sizes, int n_in,
                              void* d_out, int out_size, void* d_ws, size_t ws_size,
                              hipStream_t stream) {
    (void)in_sizes; (void)n_in; (void)out_size; (void)ws_size;
    const float* x   = (const float*)d_in[0];
    const float* d1w = (const float*)d_in[1];
    const float* d1b = (const float*)d_in[2];
    const float* g1w = (const float*)d_in[3];
    const float* g1b = (const float*)d_in[4];
    const float* s1w = (const float*)d_in[5];
    const float* s1b = (const float*)d_in[6];
    const float* d2w = (const float*)d_in[7];
    const float* d2b = (const float*)d_in[8];
    const float* g2w = (const float*)d_in[9];
    const float* g2b = (const float*)d_in[10];
    const float* s2w = (const float*)d_in[11];
    const float* s2b = (const float*)d_in[12];
    const float* d3w = (const float*)d_in[13];
    const float* d3b = (const float*)d_in[14];
    const float* g3w = (const float*)d_in[15];
    const float* g3b = (const float*)d_in[16];
    const float* d4w = (const float*)d_in[17];
    const float* d4b = (const float*)d_in[18];
    const float* g4w = (const float*)d_in[19];
    const float* g4b = (const float*)d_in[20];
    const float* fw  = (const float*)d_in[21];
    const float* fb  = (const float*)d_in[22];
    float* out = (float*)d_out;

    float* ws  = (float*)d_ws;
    float* s7  = ws;                  // 16*128*49      = 100352
    float* s14 = s7  + 100352;        // 16*128*196     = 401408
    float* s28 = s14 + 401408;        // 16*128*784     = 1605632
    float* sk1 = s28 + 1605632;       // 16*32*196      = 100352
    float* sk2 = sk1 + 100352;        // 16*16*784      = 200704
    float* h1  = sk2 + 200704;        // 16*32*196      = 100352
    float* h2  = h1  + 100352;        // 16*16*784      = 200704
    float* h3  = h2  + 200704;        // 16*8*3136      = 401408
    float* h4  = h3  + 401408;        // 16*4*12544     = 802816
    float* pre = h4  + 802816;        // 16*2*50176     = 1605632
    float2* pst1 = (float2*)(pre + 1605632);   // 16*8  * 1  = 128 pairs
    float2* pst2 = pst1 + 128;                 // 16*4  * 7  = 448 pairs
    float2* pst3 = pst2 + 448;                 // 16*2  * 14 = 448 pairs
    float2* pst4 = pst3 + 448;                 // 16*1  * 56 = 896 pairs

    // ---- SIFT features ----
    sift_kernel<32, 7, 256><<<784,   256, 0, stream>>>(x, s7);
    sift_kernel<16,14, 256><<<3136,  256, 0, stream>>>(x, s14);
    sift_kernel< 8,28, 128><<<12544, 128, 0, stream>>>(x, s28);

    // ---- skip connections (flat-layout conv1x1, proven correct) ----
    conv1x1<32, 196><<<98,  256, 0, stream>>>(s14, s1w, s1b, sk1);
    conv1x1<16, 784><<<196, 256, 0, stream>>>(s28, s2w, s2b, sk2);

    // L1: convT(128->32, 7->14), GN(8). NCH=4=CG -> one block per (b,g). NBLK_OUT=1.
    convt_tiled<128, 0, 32, 8,  7, 4, 14, 256, false, 1, 1, 1, 1>
        <<<dim3(1, 16*8), 256, 0, stream>>>(s7, nullptr, d1w, d1b, nullptr, nullptr, nullptr, h1, pst1);
    // L2: convT(64->16, 14->28), GN(4). in via GN(8,784,NBLK_IN=1). grid (7,32). NBLK_OUT=7.
    convt_tiled< 32,32, 16, 4, 14, 8,  4, 128, true, 8, 784, 1, 7>
        <<<dim3(7, 16*2), 128, 0, stream>>>(h1, sk1, d2w, d2b, pst1, g1w, g1b, h2, pst2);
    // L3: convT(32->8, 28->56), GN(2). in via GN(4,3136,NBLK_IN=7). grid (14,16). NBLK_OUT=14.
    convt_tiled< 16,16,  8, 2, 28, 8,  4, 256, true, 4, 3136, 7, 14>
        <<<dim3(14, 16), 256, 0, stream>>>(h2, sk2, d3w, d3b, pst2, g2w, g2b, h3, pst3);
    // L4: convT(8->4, 56->112), GN(1). in via GN(2,12544,NBLK_IN=14). grid (56,16). NBLK_OUT=56.
    convt_tiled<  8, 0,  4, 1, 56, 4,  2, 256, true, 2, 12544, 14, 56>
        <<<dim3(56, 16), 256, 0, stream>>>(h3, nullptr, d4w, d4b, pst3, g3w, g3b, h4, pst4);

    // head
    convt_final_fused<<<dim3(196, 16), 256, 0, stream>>>(h4, fw, fb, pst4, g4w, g4b, pre);
    bilateral_tiled<<<dim3(14, 14, 16), 256, 0, stream>>>(x, pre, out);
}